// Round 5
// baseline (433.583 us; speedup 1.0000x reference)
//
#include <hip/hip_runtime.h>
#include <hip/hip_bf16.h>
#include <hip/hip_fp16.h>

// GCN: 3x (h@W -> symmetric-norm edge aggregation -> +b -> relu),
// segment_max pool over sorted batch, 2-layer MLP head.
// R18: row-per-lane-group gathers. R17 falsifier fired (bytes halved,
// time unchanged) -> k_agg is transaction/latency-bound, ~2 outstanding
// gathers/wave. New layout: 4 lanes per edge (each loads a 16B dwordx4
// quarter of the 64B fp16 row) -> ONE gather instruction fetches 16
// distinct rows (was 2). ds_bpermute per edge drops 8x (2 shfls per
// 16 edges + per-node 4-step shfl_xor reduce). k_agg16: 2 lanes/row ->
// 32 rows per instruction. fp16 tables kept from R17.

#define WG 256
#define CAP 9216      // bucket capacity: mean 8192, sigma ~90 -> +11 sigma
#define T_EDGES 16384 // edges per bucketing block

__device__ __forceinline__ float2 cvt2(unsigned u) {
    __half2 h = *reinterpret_cast<__half2*>(&u);
    return __half22float2(h);
}

__global__ void k_init(int* bcur, float* pooled, int nb16, int pooledN) {
    int i = blockIdx.x * blockDim.x + threadIdx.x;
    if (i < nb16) bcur[i] = 0;
    if (i < pooledN) pooled[i] = 0.0f;
}

// Phase 1: tile-local counting scatter into 256-node buckets.
// Record packs low: (col&255) | (row<<8)   high: w bits.
__global__ __launch_bounds__(1024)
void k_bucket(const int* __restrict__ row, const int* __restrict__ col,
              const float* __restrict__ w,
              int* bcur, int2* __restrict__ buck, int E, int NB) {
    __shared__ int hist[512];
    __shared__ int base[512];
    int tid = threadIdx.x;
    for (int i = tid; i < NB; i += 1024) hist[i] = 0;
    __syncthreads();
    int start = blockIdx.x * T_EDGES;
    int end = min(start + T_EDGES, E);
    for (int i = start + tid; i < end; i += 1024)
        atomicAdd(&hist[col[i] >> 8], 1);
    __syncthreads();
    for (int i = tid; i < NB; i += 1024) {
        int h = hist[i];
        base[i] = (h > 0) ? atomicAdd(&bcur[i * 16], h) : 0;  // reserve run
        hist[i] = 0;
    }
    __syncthreads();
    for (int i = start + tid; i < end; i += 1024) {
        int c = col[i];
        int b = c >> 8;
        int off = atomicAdd(&hist[b], 1);
        int pos = base[b] + off;
        if (pos < CAP) {
            int2 pk;
            pk.x = (c & 255) | (row[i] << 8);
            pk.y = __float_as_int(w[i]);
            buck[(size_t)b * CAP + pos] = pk;
        }
    }
}

// Fused phase 2 (incl. bucket-level scan): per bucket --
// scan bcur in LDS -> bbase; pass 1: LDS count+wsum over records; write
// dis; in-bucket prefix -> ptr + cursors; pass 2 (L2-hot re-read):
// scatter records to final CSR as (row, raw w).
__global__ __launch_bounds__(1024)
void k_fuse(const int* __restrict__ bcur, const int2* __restrict__ buck,
            float* __restrict__ dis, int* __restrict__ ptr,
            int2* __restrict__ csr, int N, int NB) {
    __shared__ int lc[256];
    __shared__ float lw[256];
    __shared__ int sh[256];
    __shared__ int cur[256];
    __shared__ int sb[512];
    int b = blockIdx.x;
    int tid = threadIdx.x;
    if (tid < 512) sb[tid] = (tid < NB) ? min(bcur[tid * 16], CAP) : 0;
    if (tid < 256) { lc[tid] = 0; lw[tid] = 0.0f; }
    __syncthreads();
    for (int off = 1; off < 512; off <<= 1) {
        int v = (tid < 512 && tid >= off) ? sb[tid - off] : 0;
        __syncthreads();
        if (tid < 512) sb[tid] += v;
        __syncthreads();
    }
    int m = min(bcur[b * 16], CAP);
    int bbase = sb[b] - m;               // exclusive prefix for this bucket
    if (b == 0 && tid == 0) ptr[N] = sb[511];  // grand total
    const int2* bp = buck + (size_t)b * CAP;
    for (int i = tid; i < m; i += 1024) {
        int2 pk = bp[i];
        int lcol = pk.x & 255;
        atomicAdd(&lc[lcol], 1);
        atomicAdd(&lw[lcol], __int_as_float(pk.y));
    }
    __syncthreads();
    int lcnt = 0;
    if (tid < 256) { lcnt = lc[tid]; sh[tid] = lcnt; }
    __syncthreads();
    for (int off = 1; off < 256; off <<= 1) {
        int t = (tid >= off && tid < 256) ? sh[tid - off] : 0;
        __syncthreads();
        if (tid < 256) sh[tid] += t;
        __syncthreads();
    }
    int node = (b << 8) + tid;
    if (tid < 256) {
        int base = bbase + sh[tid] - lcnt;  // exclusive node prefix
        cur[tid] = base;
        if (node < N) {
            ptr[node] = base;
            float d = 1.0f + lw[tid];   // self-loop weight 1
            dis[node] = (d > 0.0f) ? (1.0f / sqrtf(d)) : 0.0f;
        }
    }
    __syncthreads();
    for (int i = tid; i < m; i += 1024) {
        int2 pk = bp[i];
        int lcol = pk.x & 255;
        int pos = atomicAdd(&cur[lcol], 1);
        int2 rec;
        rec.x = (int)(((unsigned)pk.x) >> 8);
        rec.y = pk.y;                    // raw w (dis folded into features)
        csr[pos] = rec;
    }
}

// x' = dis[node] * x[node]  into N x 16 fp16 rows (cols 10-15 zero)
__global__ void k_stage(const float* __restrict__ x, const float* __restrict__ dis,
                        __half* __restrict__ xp, int n) {
    int gid = blockIdx.x * blockDim.x + threadIdx.x;
    int node = gid >> 4, f = gid & 15;
    if (node < n)
        xp[(size_t)node * 16 + f] = __float2half((f < 10) ? dis[node] * x[(size_t)node * 10 + f] : 0.0f);
}

// y[c] = dis[c] * ( sum_e w_e * x'[row_e] + x'[c] )   (fp16 32B rows)
// One wave per node. 2 lanes per edge-row: esub=lane>>1 (0..31),
// qh=lane&1 loads 16B (8 halves). One gather instr = 32 distinct rows.
// 5-step shfl_xor reduce over lanes sharing qh; lanes 0-1 finalize.
__global__ __launch_bounds__(256)
void k_agg16(const __half* __restrict__ xp, const float* __restrict__ dis,
             const int* __restrict__ ptr, const int2* __restrict__ csr,
             float* __restrict__ y, int n) {
    int wid = (blockIdx.x * blockDim.x + threadIdx.x) >> 6;
    int lane = threadIdx.x & 63;
    if (wid >= n) return;
    int esub = lane >> 1;
    int qh = lane & 1;
    int s = ptr[wid];
    int len = ptr[wid + 1] - s;
    float acc[8];
#pragma unroll
    for (int k = 0; k < 8; k++) acc[k] = 0.0f;
    for (int off = 0; off < len; off += 32) {
        int idxv = 0; float nrmv = 0.0f;
        if (lane < 32 && off + lane < len) {
            int2 v = csr[s + off + lane];
            idxv = v.x;
            nrmv = __int_as_float(v.y);
        }
        int r = __shfl(idxv, esub, 64);
        float w = __shfl(nrmv, esub, 64);          // 0 past end -> row0 * 0
        uint4 U = *reinterpret_cast<const uint4*>(xp + (size_t)r * 16 + qh * 8);
        float2 f0 = cvt2(U.x), f1 = cvt2(U.y), f2 = cvt2(U.z), f3 = cvt2(U.w);
        acc[0] = fmaf(w, f0.x, acc[0]); acc[1] = fmaf(w, f0.y, acc[1]);
        acc[2] = fmaf(w, f1.x, acc[2]); acc[3] = fmaf(w, f1.y, acc[3]);
        acc[4] = fmaf(w, f2.x, acc[4]); acc[5] = fmaf(w, f2.y, acc[5]);
        acc[6] = fmaf(w, f3.x, acc[6]); acc[7] = fmaf(w, f3.y, acc[7]);
    }
#pragma unroll
    for (int m = 2; m <= 32; m <<= 1) {
#pragma unroll
        for (int k = 0; k < 8; k++) acc[k] += __shfl_xor(acc[k], m, 64);
    }
    if (lane < 2) {                                 // lane == qh owner
        float dc = dis[wid];
        uint4 S = *reinterpret_cast<const uint4*>(xp + (size_t)wid * 16 + lane * 8);
        float2 s0 = cvt2(S.x), s1 = cvt2(S.y), s2 = cvt2(S.z), s3 = cvt2(S.w);
        float sf[8] = { s0.x, s0.y, s1.x, s1.y, s2.x, s2.y, s3.x, s3.y };
#pragma unroll
        for (int k = 0; k < 8; k++)
            y[(size_t)wid * 16 + lane * 8 + k] = dc * (acc[k] + sf[k]);
        // cols 10-15: xp is zero there -> writes 0
    }
}

// hw2 = dis * ( relu(y @ W1 + b1) @ W2 )  -- 8 nodes/block, LDS staged.
// Output fp16 rows (stride 32 halves = 64B).
__global__ __launch_bounds__(256)
void k_lin1(const float* __restrict__ y, const float* __restrict__ W1,
            const float* __restrict__ b1, const float* __restrict__ W2,
            const float* __restrict__ dis, __half* __restrict__ out, int n) {
    __shared__ float W1s[10 * 32];
    __shared__ float W2s[30 * 32];
    __shared__ float b1s[32];
    __shared__ float ys[8][16];
    __shared__ float hs[8][32];
    int tid = threadIdx.x;
    for (int i = tid; i < 10 * 32; i += 256) { int k = i >> 5, f = i & 31; W1s[i] = (f < 30) ? W1[k * 30 + f] : 0.0f; }
    for (int i = tid; i < 30 * 32; i += 256) { int k = i >> 5, f = i & 31; W2s[i] = (f < 30) ? W2[k * 30 + f] : 0.0f; }
    if (tid < 32) b1s[tid] = (tid < 30) ? b1[tid] : 0.0f;
    int n8 = tid >> 5, f = tid & 31;
    int node = blockIdx.x * 8 + n8;
    __syncthreads();
    if (node < n && f < 16) ys[n8][f] = y[(size_t)node * 16 + f];
    __syncthreads();
    if (node < n) {
        float h = b1s[f];
#pragma unroll
        for (int k = 0; k < 10; k++) h += ys[n8][k] * W1s[k * 32 + f];
        h = fmaxf(h, 0.0f);
        if (f >= 30) h = 0.0f;
        hs[n8][f] = h;
    }
    __syncthreads();
    if (node < n) {
        float o = 0.0f;
#pragma unroll
        for (int k = 0; k < 30; k++) o += hs[n8][k] * W2s[k * 32 + f];
        out[(size_t)node * 32 + f] = __float2half(o * dis[node]);  // cols>=30 are 0
    }
}

// hw' = dis[node] * (in @ W)   (W is 30 x 30 row-major), in fp32,
// out fp16 rows stride 32 (cols 30,31 zeroed).
__global__ void k_matmul30(const float* __restrict__ in,
                           const float* __restrict__ W, const float* __restrict__ dis,
                           __half* __restrict__ out, int n) {
    __shared__ float Ws[30 * 30];
    for (int idx = threadIdx.x; idx < 30 * 30; idx += blockDim.x) Ws[idx] = W[idx];
    __syncthreads();
    int gid = blockIdx.x * blockDim.x + threadIdx.x;
    int node = gid >> 5;
    int f = gid & 31;
    if (node < n) {
        float acc = 0.0f;
        if (f < 30) {
            const float* ip = in + (size_t)node * 32;
#pragma unroll
            for (int k = 0; k < 30; k++) acc += ip[k] * Ws[k * 30 + f];
            acc *= dis[node];
        }
        out[(size_t)node * 32 + f] = __float2half(acc);   // coalesced, zero pad
    }
}

// h = relu( dis[c] * ( sum_e w_e*hw'[row_e] + hw'[c] ) + b )
// One wave per node. 4 lanes per edge-row: esub=lane>>2 (0..15),
// q=lane&3 loads 16B (8 halves) of the 64B fp16 row. One gather
// instr = 16 distinct rows. 32-edge outer step: one csr load (lanes
// 0-31) feeds two 16-edge sub-chunks -> 2 gathers back-to-back.
// 4-step shfl_xor reduce over lanes sharing q; lanes 0-3 finalize.
__global__ __launch_bounds__(256)
void k_agg(const __half* __restrict__ hw, const float* __restrict__ dis,
           const int* __restrict__ ptr, const int2* __restrict__ csr,
           const float* __restrict__ bias,
           float* __restrict__ out, int n) {
    int wid = (blockIdx.x * blockDim.x + threadIdx.x) >> 6;
    int lane = threadIdx.x & 63;
    if (wid >= n) return;
    int esub = lane >> 2;
    int q = lane & 3;
    int s = ptr[wid];
    int len = ptr[wid + 1] - s;
    float acc[8];
#pragma unroll
    for (int k = 0; k < 8; k++) acc[k] = 0.0f;
    for (int off = 0; off < len; off += 32) {
        int idxv = 0; float nrmv = 0.0f;
        if (lane < 32 && off + lane < len) {
            int2 v = csr[s + off + lane];
            idxv = v.x;
            nrmv = __int_as_float(v.y);
        }
        // sub-chunk A: edges off..off+15 (csr lanes 0-15)
        int rA = __shfl(idxv, esub, 64);
        float wA = __shfl(nrmv, esub, 64);
        uint4 UA = *reinterpret_cast<const uint4*>(hw + (size_t)rA * 32 + q * 8);
        if (off + 16 < len) {
            // sub-chunk B: edges off+16..off+31 (csr lanes 16-31)
            int rB = __shfl(idxv, 16 + esub, 64);
            float wB = __shfl(nrmv, 16 + esub, 64);
            uint4 UB = *reinterpret_cast<const uint4*>(hw + (size_t)rB * 32 + q * 8);
            float2 a0 = cvt2(UA.x), a1 = cvt2(UA.y), a2 = cvt2(UA.z), a3 = cvt2(UA.w);
            acc[0] = fmaf(wA, a0.x, acc[0]); acc[1] = fmaf(wA, a0.y, acc[1]);
            acc[2] = fmaf(wA, a1.x, acc[2]); acc[3] = fmaf(wA, a1.y, acc[3]);
            acc[4] = fmaf(wA, a2.x, acc[4]); acc[5] = fmaf(wA, a2.y, acc[5]);
            acc[6] = fmaf(wA, a3.x, acc[6]); acc[7] = fmaf(wA, a3.y, acc[7]);
            float2 b0 = cvt2(UB.x), b1 = cvt2(UB.y), b2 = cvt2(UB.z), b3 = cvt2(UB.w);
            acc[0] = fmaf(wB, b0.x, acc[0]); acc[1] = fmaf(wB, b0.y, acc[1]);
            acc[2] = fmaf(wB, b1.x, acc[2]); acc[3] = fmaf(wB, b1.y, acc[3]);
            acc[4] = fmaf(wB, b2.x, acc[4]); acc[5] = fmaf(wB, b2.y, acc[5]);
            acc[6] = fmaf(wB, b3.x, acc[6]); acc[7] = fmaf(wB, b3.y, acc[7]);
        } else {
            float2 a0 = cvt2(UA.x), a1 = cvt2(UA.y), a2 = cvt2(UA.z), a3 = cvt2(UA.w);
            acc[0] = fmaf(wA, a0.x, acc[0]); acc[1] = fmaf(wA, a0.y, acc[1]);
            acc[2] = fmaf(wA, a1.x, acc[2]); acc[3] = fmaf(wA, a1.y, acc[3]);
            acc[4] = fmaf(wA, a2.x, acc[4]); acc[5] = fmaf(wA, a2.y, acc[5]);
            acc[6] = fmaf(wA, a3.x, acc[6]); acc[7] = fmaf(wA, a3.y, acc[7]);
        }
    }
#pragma unroll
    for (int m = 4; m <= 32; m <<= 1) {
#pragma unroll
        for (int k = 0; k < 8; k++) acc[k] += __shfl_xor(acc[k], m, 64);
    }
    if (lane < 4) {                                 // lane == q owner
        float dc = dis[wid];
        uint4 S = *reinterpret_cast<const uint4*>(hw + (size_t)wid * 32 + lane * 8);
        float2 s0 = cvt2(S.x), s1 = cvt2(S.y), s2 = cvt2(S.z), s3 = cvt2(S.w);
        float sf[8] = { s0.x, s0.y, s1.x, s1.y, s2.x, s2.y, s3.x, s3.y };
#pragma unroll
        for (int k = 0; k < 8; k++) {
            int f = lane * 8 + k;
            if (f < 30) {
                float r = dc * (acc[k] + sf[k]) + bias[f];
                out[(size_t)wid * 32 + f] = fmaxf(r, 0.0f);
            }
        }
    }
}

// segment_max over sorted batch; 32 lanes (features) x 64-node chunks,
// run-length max in registers, atomicMax(int) flush (values >= 0 post-relu).
__global__ void k_pool(const float* __restrict__ h, const int* __restrict__ batch,
                       float* pooled, int n) {
    int gid = blockIdx.x * blockDim.x + threadIdx.x;
    int chunk = gid >> 5;
    int f = gid & 31;
    int n0 = chunk * 64;
    if (n0 >= n || f >= 30) return;
    int end = min(n0 + 64, n);
    int curg = batch[n0];
    float m = 0.0f;
    for (int i = n0; i < end; i++) {
        int g = batch[i];
        if (g != curg) {
            atomicMax((int*)&pooled[curg * 32 + f], __float_as_int(m));
            m = 0.0f;
            curg = g;
        }
        m = fmaxf(m, h[(size_t)i * 32 + f]);
    }
    atomicMax((int*)&pooled[curg * 32 + f], __float_as_int(m));
}

__global__ void k_mlp(const float* __restrict__ pooled,
                      const float* __restrict__ LW1, const float* __restrict__ Lb1,
                      const float* __restrict__ LW2, const float* __restrict__ Lb2,
                      float* __restrict__ out, int G) {
    int g = blockIdx.x * blockDim.x + threadIdx.x;
    if (g >= G) return;
    float p[30];
#pragma unroll
    for (int k = 0; k < 30; k++) p[k] = pooled[g * 32 + k];
    float o0 = Lb2[0], o1 = Lb2[1];
#pragma unroll
    for (int j = 0; j < 10; j++) {
        float hj = Lb1[j];
#pragma unroll
        for (int k = 0; k < 30; k++) hj += p[k] * LW1[k * 10 + j];
        hj = fmaxf(hj, 0.0f);
        o0 += hj * LW2[j * 2 + 0];
        o1 += hj * LW2[j * 2 + 1];
    }
    out[g * 2 + 0] = o0;
    out[g * 2 + 1] = o1;
}

extern "C" void kernel_launch(void* const* d_in, const int* in_sizes, int n_in,
                              void* d_out, int out_size, void* d_ws, size_t ws_size,
                              hipStream_t stream) {
    const float* x     = (const float*)d_in[0];
    const int*   ei    = (const int*)d_in[1];
    const int*   batch = (const int*)d_in[2];
    const float* ew    = (const float*)d_in[3];
    const float* W1 = (const float*)d_in[4];  const float* b1  = (const float*)d_in[5];
    const float* W2 = (const float*)d_in[6];  const float* b2  = (const float*)d_in[7];
    const float* W3 = (const float*)d_in[8];  const float* b3  = (const float*)d_in[9];
    const float* LW1 = (const float*)d_in[10]; const float* Lb1 = (const float*)d_in[11];
    const float* LW2 = (const float*)d_in[12]; const float* Lb2 = (const float*)d_in[13];
    float* out = (float*)d_out;

    const int N = in_sizes[2];       // batch has N entries
    const int E = in_sizes[3];       // edge_weights has E entries
    const int G = out_size / 2;
    const int* row = ei;
    const int* col = ei + E;

    const int NB = (N + 255) >> 8;   // 391 buckets (must be <= 512)

    char* p = (char*)d_ws;
    auto carve = [&](size_t bytes) -> void* {
        void* r = (void*)p;
        p += (bytes + 255) & ~(size_t)255;
        return r;
    };
    int*   ptr       = (int*)carve((size_t)(N + 1) * 4);
    float* dis       = (float*)carve((size_t)N * 4);
    int*   bcur      = (int*)carve((size_t)NB * 16 * 4);
    int2*  csr       = (int2*)carve((size_t)E * 8);
    // regionA: bucket storage (build) aliased with feature buffers (layers).
    // Layer layout: [bufA fp32: N*32*4][bufB fp16: N*32*2]. xp (fp16,
    // N*16*2) at offset 0 and y16 (fp32, N*16*4) at offset N*16*2 both
    // alias bufA; both are dead before layer-2 k_agg writes bufA.
    size_t buckBytes = (size_t)NB * CAP * 8;
    size_t featBytes = (size_t)N * 32 * 4 * 2;
    char*  regionA   = (char*)carve(buckBytes > featBytes ? buckBytes : featBytes);
    int2*  buck      = (int2*)regionA;
    float* bufA      = (float*)regionA;
    __half* xp       = (__half*)regionA;                            // N*16 fp16
    float* y16       = (float*)(regionA + (size_t)N * 16 * 2);      // N*16 fp32
    __half* bufB     = (__half*)(regionA + (size_t)N * 32 * 4);     // N*32 fp16
    float* pooled    = (float*)carve((size_t)G * 32 * 4);

    int initN = (NB * 16 > G * 32) ? NB * 16 : G * 32;

    // --- build CSR ---
    k_init<<<(initN + WG - 1) / WG, WG, 0, stream>>>(bcur, pooled, NB * 16, G * 32);
    k_bucket<<<(E + T_EDGES - 1) / T_EDGES, 1024, 0, stream>>>(row, col, ew, bcur, buck, E, NB);
    k_fuse<<<NB, 1024, 0, stream>>>(bcur, buck, dis, ptr, csr, N, NB);

    int agg_grid = (int)(((size_t)N * 64 + WG - 1) / WG);   // 1 node/wave (both aggs)
    int mm_grid  = (int)(((size_t)N * 32 + WG - 1) / WG);

    // layer 1 in 10-dim space: y = dc*(sum w*x'_r + x'_c), then lin1
    k_stage<<<(int)(((size_t)N * 16 + WG - 1) / WG), WG, 0, stream>>>(x, dis, xp, N);
    k_agg16<<<agg_grid, WG, 0, stream>>>(xp, dis, ptr, csr, y16, N);
    k_lin1<<<(N + 7) / 8, 256, 0, stream>>>(y16, W1, b1, W2, dis, bufB, N);   // bufB = hw2 (fp16)
    // layer 2
    k_agg<<<agg_grid, WG, 0, stream>>>(bufB, dis, ptr, csr, b2, bufA, N);     // bufA = h2 (fp32)
    k_matmul30<<<mm_grid, WG, 0, stream>>>(bufA, W3, dis, bufB, N);           // bufB = hw3 (fp16)
    // layer 3
    k_agg<<<agg_grid, WG, 0, stream>>>(bufB, dis, ptr, csr, b3, bufA, N);     // bufA = h3 (fp32)

    // pool + head
    int pool_grid = (int)((((size_t)(N + 63) / 64) * 32 + WG - 1) / WG);
    k_pool<<<pool_grid, WG, 0, stream>>>(bufA, batch, pooled, N);
    k_mlp<<<(G + WG - 1) / WG, WG, 0, stream>>>(pooled, LW1, Lb1, LW2, Lb2, out, G);
}

// Round 6
// 403.403 us; speedup vs baseline: 1.0748x; 1.0748x over previous
//
#include <hip/hip_runtime.h>
#include <hip/hip_bf16.h>
#include <hip/hip_fp16.h>

// GCN: 3x (h@W -> symmetric-norm edge aggregation -> +b -> relu),
// segment_max pool over sorted batch, 2-layer MLP head.
// R19: (a) revert agg structure to R17 (best k_agg form, 61us);
// (b) NON-TEMPORAL hints on streaming accesses (csr reads, feature-row
// writes): the 25.6MB csr stream + 12.5MB writes were evicting the
// 6.4MB fp16 gather table from L2 every dispatch (FETCH=112MB => ~80MB
// table re-fetch, 40% gather miss to L3). Evict-first streams keep the
// table L2-resident -> per-miss latency ~130->~90ns at the same
// in-flight cap. (c) fuse segment-max pool into layer-3 k_agg epilogue
// via global atomicMax (h3 existed only to be pooled): kills k_pool +
// 25MB round trip.

#define WG 256
#define CAP 9216      // bucket capacity: mean 8192, sigma ~90 -> +11 sigma
#define T_EDGES 16384 // edges per bucketing block

__global__ void k_init(int* bcur, float* pooled, int nb16, int pooledN) {
    int i = blockIdx.x * blockDim.x + threadIdx.x;
    if (i < nb16) bcur[i] = 0;
    if (i < pooledN) pooled[i] = 0.0f;
}

// Phase 1: tile-local counting scatter into 256-node buckets.
// Record packs low: (col&255) | (row<<8)   high: w bits.
__global__ __launch_bounds__(1024)
void k_bucket(const int* __restrict__ row, const int* __restrict__ col,
              const float* __restrict__ w,
              int* bcur, int2* __restrict__ buck, int E, int NB) {
    __shared__ int hist[512];
    __shared__ int base[512];
    int tid = threadIdx.x;
    for (int i = tid; i < NB; i += 1024) hist[i] = 0;
    __syncthreads();
    int start = blockIdx.x * T_EDGES;
    int end = min(start + T_EDGES, E);
    for (int i = start + tid; i < end; i += 1024)
        atomicAdd(&hist[col[i] >> 8], 1);
    __syncthreads();
    for (int i = tid; i < NB; i += 1024) {
        int h = hist[i];
        base[i] = (h > 0) ? atomicAdd(&bcur[i * 16], h) : 0;  // reserve run
        hist[i] = 0;
    }
    __syncthreads();
    for (int i = start + tid; i < end; i += 1024) {
        int c = col[i];
        int b = c >> 8;
        int off = atomicAdd(&hist[b], 1);
        int pos = base[b] + off;
        if (pos < CAP) {
            int2 pk;
            pk.x = (c & 255) | (row[i] << 8);
            pk.y = __float_as_int(w[i]);
            buck[(size_t)b * CAP + pos] = pk;
        }
    }
}

// Fused phase 2 (incl. bucket-level scan): per bucket --
// scan bcur in LDS -> bbase; pass 1: LDS count+wsum over records; write
// dis; in-bucket prefix -> ptr + cursors; pass 2 (L2-hot re-read):
// scatter records to final CSR as (row, raw w).
__global__ __launch_bounds__(1024)
void k_fuse(const int* __restrict__ bcur, const int2* __restrict__ buck,
            float* __restrict__ dis, int* __restrict__ ptr,
            int2* __restrict__ csr, int N, int NB) {
    __shared__ int lc[256];
    __shared__ float lw[256];
    __shared__ int sh[256];
    __shared__ int cur[256];
    __shared__ int sb[512];
    int b = blockIdx.x;
    int tid = threadIdx.x;
    if (tid < 512) sb[tid] = (tid < NB) ? min(bcur[tid * 16], CAP) : 0;
    if (tid < 256) { lc[tid] = 0; lw[tid] = 0.0f; }
    __syncthreads();
    for (int off = 1; off < 512; off <<= 1) {
        int v = (tid < 512 && tid >= off) ? sb[tid - off] : 0;
        __syncthreads();
        if (tid < 512) sb[tid] += v;
        __syncthreads();
    }
    int m = min(bcur[b * 16], CAP);
    int bbase = sb[b] - m;               // exclusive prefix for this bucket
    if (b == 0 && tid == 0) ptr[N] = sb[511];  // grand total
    const int2* bp = buck + (size_t)b * CAP;
    for (int i = tid; i < m; i += 1024) {
        int2 pk = bp[i];
        int lcol = pk.x & 255;
        atomicAdd(&lc[lcol], 1);
        atomicAdd(&lw[lcol], __int_as_float(pk.y));
    }
    __syncthreads();
    int lcnt = 0;
    if (tid < 256) { lcnt = lc[tid]; sh[tid] = lcnt; }
    __syncthreads();
    for (int off = 1; off < 256; off <<= 1) {
        int t = (tid >= off && tid < 256) ? sh[tid - off] : 0;
        __syncthreads();
        if (tid < 256) sh[tid] += t;
        __syncthreads();
    }
    int node = (b << 8) + tid;
    if (tid < 256) {
        int base = bbase + sh[tid] - lcnt;  // exclusive node prefix
        cur[tid] = base;
        if (node < N) {
            ptr[node] = base;
            float d = 1.0f + lw[tid];   // self-loop weight 1
            dis[node] = (d > 0.0f) ? (1.0f / sqrtf(d)) : 0.0f;
        }
    }
    __syncthreads();
    for (int i = tid; i < m; i += 1024) {
        int2 pk = bp[i];
        int lcol = pk.x & 255;
        int pos = atomicAdd(&cur[lcol], 1);
        int2 rec;
        rec.x = (int)(((unsigned)pk.x) >> 8);
        rec.y = pk.y;                    // raw w (dis folded into features)
        csr[pos] = rec;
    }
}

// x' = dis[node] * x[node]  into N x 16 fp16 rows (cols 10-15 zero)
__global__ void k_stage(const float* __restrict__ x, const float* __restrict__ dis,
                        __half* __restrict__ xp, int n) {
    int gid = blockIdx.x * blockDim.x + threadIdx.x;
    int node = gid >> 4, f = gid & 15;
    if (node < n)
        xp[(size_t)node * 16 + f] = __float2half((f < 10) ? dis[node] * x[(size_t)node * 10 + f] : 0.0f);
}

// y[c] = dis[c] * ( sum_e w_e * x'[row_e] + x'[c] )   (fp16 32B rows)
// 4 nodes per wave: quarter q owns node 4*wid+q, f = lane&15. Each
// quarter loads its own 16-record CSR chunk (non-temporal: stream must
// not evict the gather table); shfl src (lane&48)|j. One gather instr
// = 4 distinct 32B segments.
__global__ __launch_bounds__(256, 4)
void k_agg16(const __half* __restrict__ xp, const float* __restrict__ dis,
             const int* __restrict__ ptr, const int2* __restrict__ csr,
             float* __restrict__ y, int n) {
    int wid = (blockIdx.x * blockDim.x + threadIdx.x) >> 6;
    int lane = threadIdx.x & 63;
    int f = lane & 15;
    int laneq = lane & 48;
    int node = 4 * wid + (lane >> 4);
    bool valid = node < n;
    int s = 0, e = 0;
    if (valid) { s = ptr[node]; e = ptr[node + 1]; }
    int len = e - s;
    int m01 = max(__shfl(len, 0, 64), __shfl(len, 16, 64));
    int m23 = max(__shfl(len, 32, 64), __shfl(len, 48, 64));
    int maxlen = max(m01, m23);
    float a0 = 0.0f, a1 = 0.0f, a2 = 0.0f, a3 = 0.0f;
    for (int off = 0; off < maxlen; off += 16) {
        int idxv = 0; float nrmv = 0.0f;
        if (off + f < len) {
            unsigned long long pk = __builtin_nontemporal_load(
                reinterpret_cast<const unsigned long long*>(csr) + (s + off + f));
            idxv = (int)(unsigned)(pk & 0xffffffffull);
            nrmv = __int_as_float((unsigned)(pk >> 32));
        }
        float wt[16], vt[16];
#pragma unroll
        for (int j = 0; j < 16; j++) {
            int r = __shfl(idxv, laneq | j, 64);
            wt[j] = __shfl(nrmv, laneq | j, 64);
            vt[j] = __half2float(xp[(size_t)r * 16 + f]);
        }
#pragma unroll
        for (int j = 0; j < 16; j += 4) {
            a0 = fmaf(wt[j],     vt[j],     a0);
            a1 = fmaf(wt[j + 1], vt[j + 1], a1);
            a2 = fmaf(wt[j + 2], vt[j + 2], a2);
            a3 = fmaf(wt[j + 3], vt[j + 3], a3);
        }
    }
    if (valid) {
        float acc = (a0 + a1) + (a2 + a3);
        float r = dis[node] * (acc + __half2float(xp[(size_t)node * 16 + f]));
        __builtin_nontemporal_store(r, &y[(size_t)node * 16 + f]);  // cols 10-15 -> 0
    }
}

// hw2 = dis * ( relu(y @ W1 + b1) @ W2 )  -- 8 nodes/block, LDS staged.
// Output fp16 rows (stride 32 halves = 64B).
__global__ __launch_bounds__(256)
void k_lin1(const float* __restrict__ y, const float* __restrict__ W1,
            const float* __restrict__ b1, const float* __restrict__ W2,
            const float* __restrict__ dis, __half* __restrict__ out, int n) {
    __shared__ float W1s[10 * 32];
    __shared__ float W2s[30 * 32];
    __shared__ float b1s[32];
    __shared__ float ys[8][16];
    __shared__ float hs[8][32];
    int tid = threadIdx.x;
    for (int i = tid; i < 10 * 32; i += 256) { int k = i >> 5, f = i & 31; W1s[i] = (f < 30) ? W1[k * 30 + f] : 0.0f; }
    for (int i = tid; i < 30 * 32; i += 256) { int k = i >> 5, f = i & 31; W2s[i] = (f < 30) ? W2[k * 30 + f] : 0.0f; }
    if (tid < 32) b1s[tid] = (tid < 30) ? b1[tid] : 0.0f;
    int n8 = tid >> 5, f = tid & 31;
    int node = blockIdx.x * 8 + n8;
    __syncthreads();
    if (node < n && f < 16) ys[n8][f] = y[(size_t)node * 16 + f];
    __syncthreads();
    if (node < n) {
        float h = b1s[f];
#pragma unroll
        for (int k = 0; k < 10; k++) h += ys[n8][k] * W1s[k * 32 + f];
        h = fmaxf(h, 0.0f);
        if (f >= 30) h = 0.0f;
        hs[n8][f] = h;
    }
    __syncthreads();
    if (node < n) {
        float o = 0.0f;
#pragma unroll
        for (int k = 0; k < 30; k++) o += hs[n8][k] * W2s[k * 32 + f];
        out[(size_t)node * 32 + f] = __float2half(o * dis[node]);  // cols>=30 are 0
    }
}

// hw' = dis[node] * (in @ W)   (W is 30 x 30 row-major), in fp32,
// out fp16 rows stride 32 (cols 30,31 zeroed).
__global__ void k_matmul30(const float* __restrict__ in,
                           const float* __restrict__ W, const float* __restrict__ dis,
                           __half* __restrict__ out, int n) {
    __shared__ float Ws[30 * 30];
    for (int idx = threadIdx.x; idx < 30 * 30; idx += blockDim.x) Ws[idx] = W[idx];
    __syncthreads();
    int gid = blockIdx.x * blockDim.x + threadIdx.x;
    int node = gid >> 5;
    int f = gid & 31;
    if (node < n) {
        float acc = 0.0f;
        if (f < 30) {
            const float* ip = in + (size_t)node * 32;
#pragma unroll
            for (int k = 0; k < 30; k++) acc += ip[k] * Ws[k * 30 + f];
            acc *= dis[node];
        }
        out[(size_t)node * 32 + f] = __float2half(acc);   // coalesced, zero pad
    }
}

// h = relu( dis[c] * ( sum_e w_e*hw'[row_e] + hw'[c] ) + b )
// One wave per node; halves process even/odd edges -> 2 distinct 64B
// segments per gather instr (fp16 rows). CSR stream read non-temporal
// (protect L2-resident table). If pooled!=nullptr: layer-3 mode, fuse
// segment_max via atomicMax (values >=0 post-relu, pooled zeroed) and
// skip the row store entirely.
__global__ __launch_bounds__(256, 4)
void k_agg(const __half* __restrict__ hw, const float* __restrict__ dis,
           const int* __restrict__ ptr, const int2* __restrict__ csr,
           const float* __restrict__ bias, const int* __restrict__ batch,
           float* __restrict__ out, float* __restrict__ pooled, int n) {
    int wid = (blockIdx.x * blockDim.x + threadIdx.x) >> 6;
    int lane = threadIdx.x & 63;
    if (wid >= n) return;
    int f = lane & 31;
    int half = lane >> 5;
    int s = ptr[wid];
    int e = ptr[wid + 1];
    float a0 = 0.0f, a1 = 0.0f, a2 = 0.0f, a3 = 0.0f;
    for (int base = s; base < e; base += 32) {
        int idxv = 0; float nrmv = 0.0f;
        int src = base + lane;
        if (lane < 32 && src < e) {
            unsigned long long pk = __builtin_nontemporal_load(
                reinterpret_cast<const unsigned long long*>(csr) + src);
            idxv = (int)(unsigned)(pk & 0xffffffffull);
            nrmv = __int_as_float((unsigned)(pk >> 32));
        }
        float wt[16], vt[16];
#pragma unroll
        for (int j = 0; j < 16; j++) {
            int sl = 2 * j + half;               // halves take even/odd edges
            int r = __shfl(idxv, sl, 64);
            wt[j] = __shfl(nrmv, sl, 64);
            vt[j] = __half2float(hw[(size_t)r * 32 + f]);
        }
#pragma unroll
        for (int j = 0; j < 16; j += 4) {
            a0 = fmaf(wt[j],     vt[j],     a0);
            a1 = fmaf(wt[j + 1], vt[j + 1], a1);
            a2 = fmaf(wt[j + 2], vt[j + 2], a2);
            a3 = fmaf(wt[j + 3], vt[j + 3], a3);
        }
    }
    float acc = (a0 + a1) + (a2 + a3);
    acc += __shfl_xor(acc, 32, 64);
    float dc = dis[wid];
    float r = dc * (acc + __half2float(hw[(size_t)wid * 32 + f]));
    if (half == 0 && f < 30) {
        r = fmaxf(r + bias[f], 0.0f);
        if (pooled) {
            int g = batch[wid];
            atomicMax((int*)&pooled[g * 32 + f], __float_as_int(r));
        } else {
            __builtin_nontemporal_store(r, &out[(size_t)wid * 32 + f]);
        }
    }
}

__global__ void k_mlp(const float* __restrict__ pooled,
                      const float* __restrict__ LW1, const float* __restrict__ Lb1,
                      const float* __restrict__ LW2, const float* __restrict__ Lb2,
                      float* __restrict__ out, int G) {
    int g = blockIdx.x * blockDim.x + threadIdx.x;
    if (g >= G) return;
    float p[30];
#pragma unroll
    for (int k = 0; k < 30; k++) p[k] = pooled[g * 32 + k];
    float o0 = Lb2[0], o1 = Lb2[1];
#pragma unroll
    for (int j = 0; j < 10; j++) {
        float hj = Lb1[j];
#pragma unroll
        for (int k = 0; k < 30; k++) hj += p[k] * LW1[k * 10 + j];
        hj = fmaxf(hj, 0.0f);
        o0 += hj * LW2[j * 2 + 0];
        o1 += hj * LW2[j * 2 + 1];
    }
    out[g * 2 + 0] = o0;
    out[g * 2 + 1] = o1;
}

extern "C" void kernel_launch(void* const* d_in, const int* in_sizes, int n_in,
                              void* d_out, int out_size, void* d_ws, size_t ws_size,
                              hipStream_t stream) {
    const float* x     = (const float*)d_in[0];
    const int*   ei    = (const int*)d_in[1];
    const int*   batch = (const int*)d_in[2];
    const float* ew    = (const float*)d_in[3];
    const float* W1 = (const float*)d_in[4];  const float* b1  = (const float*)d_in[5];
    const float* W2 = (const float*)d_in[6];  const float* b2  = (const float*)d_in[7];
    const float* W3 = (const float*)d_in[8];  const float* b3  = (const float*)d_in[9];
    const float* LW1 = (const float*)d_in[10]; const float* Lb1 = (const float*)d_in[11];
    const float* LW2 = (const float*)d_in[12]; const float* Lb2 = (const float*)d_in[13];
    float* out = (float*)d_out;

    const int N = in_sizes[2];       // batch has N entries
    const int E = in_sizes[3];       // edge_weights has E entries
    const int G = out_size / 2;
    const int* row = ei;
    const int* col = ei + E;

    const int NB = (N + 255) >> 8;   // 391 buckets (must be <= 512)

    char* p = (char*)d_ws;
    auto carve = [&](size_t bytes) -> void* {
        void* r = (void*)p;
        p += (bytes + 255) & ~(size_t)255;
        return r;
    };
    int*   ptr       = (int*)carve((size_t)(N + 1) * 4);
    float* dis       = (float*)carve((size_t)N * 4);
    int*   bcur      = (int*)carve((size_t)NB * 16 * 4);
    int2*  csr       = (int2*)carve((size_t)E * 8);
    // regionA: bucket storage (build) aliased with feature buffers (layers).
    // Layer layout: [bufA fp32: N*32*4][bufB fp16: N*32*2]. xp (fp16,
    // N*16*2) at offset 0 and y16 (fp32, N*16*4) at offset N*16*2 both
    // alias bufA; both are dead before layer-2 k_agg writes bufA.
    size_t buckBytes = (size_t)NB * CAP * 8;
    size_t featBytes = (size_t)N * 32 * 4 * 2;
    char*  regionA   = (char*)carve(buckBytes > featBytes ? buckBytes : featBytes);
    int2*  buck      = (int2*)regionA;
    float* bufA      = (float*)regionA;
    __half* xp       = (__half*)regionA;                            // N*16 fp16
    float* y16       = (float*)(regionA + (size_t)N * 16 * 2);      // N*16 fp32
    __half* bufB     = (__half*)(regionA + (size_t)N * 32 * 4);     // N*32 fp16
    float* pooled    = (float*)carve((size_t)G * 32 * 4);

    int initN = (NB * 16 > G * 32) ? NB * 16 : G * 32;

    // --- build CSR ---
    k_init<<<(initN + WG - 1) / WG, WG, 0, stream>>>(bcur, pooled, NB * 16, G * 32);
    k_bucket<<<(E + T_EDGES - 1) / T_EDGES, 1024, 0, stream>>>(row, col, ew, bcur, buck, E, NB);
    k_fuse<<<NB, 1024, 0, stream>>>(bcur, buck, dis, ptr, csr, N, NB);

    int agg_grid   = (int)(((size_t)N * 64 + WG - 1) / WG);              // 1 node/wave
    int agg16_grid = (int)(((size_t)((N + 3) / 4) * 64 + WG - 1) / WG);  // 4 nodes/wave
    int mm_grid    = (int)(((size_t)N * 32 + WG - 1) / WG);

    // layer 1 in 10-dim space: y = dc*(sum w*x'_r + x'_c), then lin1
    k_stage<<<(int)(((size_t)N * 16 + WG - 1) / WG), WG, 0, stream>>>(x, dis, xp, N);
    k_agg16<<<agg16_grid, WG, 0, stream>>>(xp, dis, ptr, csr, y16, N);
    k_lin1<<<(N + 7) / 8, 256, 0, stream>>>(y16, W1, b1, W2, dis, bufB, N);   // bufB = hw2 (fp16)
    // layer 2
    k_agg<<<agg_grid, WG, 0, stream>>>(bufB, dis, ptr, csr, b2, batch, bufA, nullptr, N); // bufA = h2
    k_matmul30<<<mm_grid, WG, 0, stream>>>(bufA, W3, dis, bufB, N);           // bufB = hw3 (fp16)
    // layer 3 + fused segment-max pool
    k_agg<<<agg_grid, WG, 0, stream>>>(bufB, dis, ptr, csr, b3, batch, nullptr, pooled, N);

    // head
    k_mlp<<<(G + WG - 1) / WG, WG, 0, stream>>>(pooled, LW1, Lb1, LW2, Lb2, out, G);
}

// Round 7
// 396.831 us; speedup vs baseline: 1.0926x; 1.0166x over previous
//
#include <hip/hip_runtime.h>
#include <hip/hip_bf16.h>
#include <hip/hip_fp16.h>

// GCN: 3x (h@W -> symmetric-norm edge aggregation -> +b -> relu),
// segment_max pool over sorted batch, 2-layer MLP head.
// R20: revert R19's non-temporal hints (k_agg 61->77us: NT load on the
// serial csr->shfl->gather path bypassed L1 and FETCH barely moved ->
// eviction theory falsified). KEEP the R19 pool fusion (worth ~45us):
// layer-3 k_agg does segment_max via atomicMax epilogue, k_pool and the
// h3 store/reload round trip are gone. fp16 gather tables from R17.

#define WG 256
#define CAP 9216      // bucket capacity: mean 8192, sigma ~90 -> +11 sigma
#define T_EDGES 16384 // edges per bucketing block

__global__ void k_init(int* bcur, float* pooled, int nb16, int pooledN) {
    int i = blockIdx.x * blockDim.x + threadIdx.x;
    if (i < nb16) bcur[i] = 0;
    if (i < pooledN) pooled[i] = 0.0f;
}

// Phase 1: tile-local counting scatter into 256-node buckets.
// Record packs low: (col&255) | (row<<8)   high: w bits.
__global__ __launch_bounds__(1024)
void k_bucket(const int* __restrict__ row, const int* __restrict__ col,
              const float* __restrict__ w,
              int* bcur, int2* __restrict__ buck, int E, int NB) {
    __shared__ int hist[512];
    __shared__ int base[512];
    int tid = threadIdx.x;
    for (int i = tid; i < NB; i += 1024) hist[i] = 0;
    __syncthreads();
    int start = blockIdx.x * T_EDGES;
    int end = min(start + T_EDGES, E);
    for (int i = start + tid; i < end; i += 1024)
        atomicAdd(&hist[col[i] >> 8], 1);
    __syncthreads();
    for (int i = tid; i < NB; i += 1024) {
        int h = hist[i];
        base[i] = (h > 0) ? atomicAdd(&bcur[i * 16], h) : 0;  // reserve run
        hist[i] = 0;
    }
    __syncthreads();
    for (int i = start + tid; i < end; i += 1024) {
        int c = col[i];
        int b = c >> 8;
        int off = atomicAdd(&hist[b], 1);
        int pos = base[b] + off;
        if (pos < CAP) {
            int2 pk;
            pk.x = (c & 255) | (row[i] << 8);
            pk.y = __float_as_int(w[i]);
            buck[(size_t)b * CAP + pos] = pk;
        }
    }
}

// Fused phase 2 (incl. bucket-level scan): per bucket --
// scan bcur in LDS -> bbase; pass 1: LDS count+wsum over records; write
// dis; in-bucket prefix -> ptr + cursors; pass 2 (L2-hot re-read):
// scatter records to final CSR as (row, raw w).
__global__ __launch_bounds__(1024)
void k_fuse(const int* __restrict__ bcur, const int2* __restrict__ buck,
            float* __restrict__ dis, int* __restrict__ ptr,
            int2* __restrict__ csr, int N, int NB) {
    __shared__ int lc[256];
    __shared__ float lw[256];
    __shared__ int sh[256];
    __shared__ int cur[256];
    __shared__ int sb[512];
    int b = blockIdx.x;
    int tid = threadIdx.x;
    if (tid < 512) sb[tid] = (tid < NB) ? min(bcur[tid * 16], CAP) : 0;
    if (tid < 256) { lc[tid] = 0; lw[tid] = 0.0f; }
    __syncthreads();
    for (int off = 1; off < 512; off <<= 1) {
        int v = (tid < 512 && tid >= off) ? sb[tid - off] : 0;
        __syncthreads();
        if (tid < 512) sb[tid] += v;
        __syncthreads();
    }
    int m = min(bcur[b * 16], CAP);
    int bbase = sb[b] - m;               // exclusive prefix for this bucket
    if (b == 0 && tid == 0) ptr[N] = sb[511];  // grand total
    const int2* bp = buck + (size_t)b * CAP;
    for (int i = tid; i < m; i += 1024) {
        int2 pk = bp[i];
        int lcol = pk.x & 255;
        atomicAdd(&lc[lcol], 1);
        atomicAdd(&lw[lcol], __int_as_float(pk.y));
    }
    __syncthreads();
    int lcnt = 0;
    if (tid < 256) { lcnt = lc[tid]; sh[tid] = lcnt; }
    __syncthreads();
    for (int off = 1; off < 256; off <<= 1) {
        int t = (tid >= off && tid < 256) ? sh[tid - off] : 0;
        __syncthreads();
        if (tid < 256) sh[tid] += t;
        __syncthreads();
    }
    int node = (b << 8) + tid;
    if (tid < 256) {
        int base = bbase + sh[tid] - lcnt;  // exclusive node prefix
        cur[tid] = base;
        if (node < N) {
            ptr[node] = base;
            float d = 1.0f + lw[tid];   // self-loop weight 1
            dis[node] = (d > 0.0f) ? (1.0f / sqrtf(d)) : 0.0f;
        }
    }
    __syncthreads();
    for (int i = tid; i < m; i += 1024) {
        int2 pk = bp[i];
        int lcol = pk.x & 255;
        int pos = atomicAdd(&cur[lcol], 1);
        int2 rec;
        rec.x = (int)(((unsigned)pk.x) >> 8);
        rec.y = pk.y;                    // raw w (dis folded into features)
        csr[pos] = rec;
    }
}

// x' = dis[node] * x[node]  into N x 16 fp16 rows (cols 10-15 zero)
__global__ void k_stage(const float* __restrict__ x, const float* __restrict__ dis,
                        __half* __restrict__ xp, int n) {
    int gid = blockIdx.x * blockDim.x + threadIdx.x;
    int node = gid >> 4, f = gid & 15;
    if (node < n)
        xp[(size_t)node * 16 + f] = __float2half((f < 10) ? dis[node] * x[(size_t)node * 10 + f] : 0.0f);
}

// y[c] = dis[c] * ( sum_e w_e * x'[row_e] + x'[c] )   (fp16 32B rows)
// 4 nodes per wave: quarter q owns node 4*wid+q, f = lane&15. Each
// quarter loads its own 16-record CSR chunk; shfl src (lane&48)|j.
// One gather instr = 4 distinct 32B segments. Output y fp32.
__global__ __launch_bounds__(256, 4)
void k_agg16(const __half* __restrict__ xp, const float* __restrict__ dis,
             const int* __restrict__ ptr, const int2* __restrict__ csr,
             float* __restrict__ y, int n) {
    int wid = (blockIdx.x * blockDim.x + threadIdx.x) >> 6;
    int lane = threadIdx.x & 63;
    int f = lane & 15;
    int laneq = lane & 48;
    int node = 4 * wid + (lane >> 4);
    bool valid = node < n;
    int s = 0, e = 0;
    if (valid) { s = ptr[node]; e = ptr[node + 1]; }
    int len = e - s;
    int m01 = max(__shfl(len, 0, 64), __shfl(len, 16, 64));
    int m23 = max(__shfl(len, 32, 64), __shfl(len, 48, 64));
    int maxlen = max(m01, m23);
    float a0 = 0.0f, a1 = 0.0f, a2 = 0.0f, a3 = 0.0f;
    for (int off = 0; off < maxlen; off += 16) {
        int idxv = 0; float nrmv = 0.0f;
        if (off + f < len) {
            int2 v = csr[s + off + f];
            idxv = v.x;
            nrmv = __int_as_float(v.y);
        }
        float wt[16], vt[16];
#pragma unroll
        for (int j = 0; j < 16; j++) {
            int r = __shfl(idxv, laneq | j, 64);
            wt[j] = __shfl(nrmv, laneq | j, 64);
            vt[j] = __half2float(xp[(size_t)r * 16 + f]);
        }
#pragma unroll
        for (int j = 0; j < 16; j += 4) {
            a0 = fmaf(wt[j],     vt[j],     a0);
            a1 = fmaf(wt[j + 1], vt[j + 1], a1);
            a2 = fmaf(wt[j + 2], vt[j + 2], a2);
            a3 = fmaf(wt[j + 3], vt[j + 3], a3);
        }
    }
    if (valid) {
        float acc = (a0 + a1) + (a2 + a3);
        float r = dis[node] * (acc + __half2float(xp[(size_t)node * 16 + f]));
        y[(size_t)node * 16 + f] = r;   // cols 10-15 compute to 0
    }
}

// hw2 = dis * ( relu(y @ W1 + b1) @ W2 )  -- 8 nodes/block, LDS staged.
// Output fp16 rows (stride 32 halves = 64B).
__global__ __launch_bounds__(256)
void k_lin1(const float* __restrict__ y, const float* __restrict__ W1,
            const float* __restrict__ b1, const float* __restrict__ W2,
            const float* __restrict__ dis, __half* __restrict__ out, int n) {
    __shared__ float W1s[10 * 32];
    __shared__ float W2s[30 * 32];
    __shared__ float b1s[32];
    __shared__ float ys[8][16];
    __shared__ float hs[8][32];
    int tid = threadIdx.x;
    for (int i = tid; i < 10 * 32; i += 256) { int k = i >> 5, f = i & 31; W1s[i] = (f < 30) ? W1[k * 30 + f] : 0.0f; }
    for (int i = tid; i < 30 * 32; i += 256) { int k = i >> 5, f = i & 31; W2s[i] = (f < 30) ? W2[k * 30 + f] : 0.0f; }
    if (tid < 32) b1s[tid] = (tid < 30) ? b1[tid] : 0.0f;
    int n8 = tid >> 5, f = tid & 31;
    int node = blockIdx.x * 8 + n8;
    __syncthreads();
    if (node < n && f < 16) ys[n8][f] = y[(size_t)node * 16 + f];
    __syncthreads();
    if (node < n) {
        float h = b1s[f];
#pragma unroll
        for (int k = 0; k < 10; k++) h += ys[n8][k] * W1s[k * 32 + f];
        h = fmaxf(h, 0.0f);
        if (f >= 30) h = 0.0f;
        hs[n8][f] = h;
    }
    __syncthreads();
    if (node < n) {
        float o = 0.0f;
#pragma unroll
        for (int k = 0; k < 30; k++) o += hs[n8][k] * W2s[k * 32 + f];
        out[(size_t)node * 32 + f] = __float2half(o * dis[node]);  // cols>=30 are 0
    }
}

// hw' = dis[node] * (in @ W)   (W is 30 x 30 row-major), in fp32,
// out fp16 rows stride 32 (cols 30,31 zeroed).
__global__ void k_matmul30(const float* __restrict__ in,
                           const float* __restrict__ W, const float* __restrict__ dis,
                           __half* __restrict__ out, int n) {
    __shared__ float Ws[30 * 30];
    for (int idx = threadIdx.x; idx < 30 * 30; idx += blockDim.x) Ws[idx] = W[idx];
    __syncthreads();
    int gid = blockIdx.x * blockDim.x + threadIdx.x;
    int node = gid >> 5;
    int f = gid & 31;
    if (node < n) {
        float acc = 0.0f;
        if (f < 30) {
            const float* ip = in + (size_t)node * 32;
#pragma unroll
            for (int k = 0; k < 30; k++) acc += ip[k] * Ws[k * 30 + f];
            acc *= dis[node];
        }
        out[(size_t)node * 32 + f] = __float2half(acc);   // coalesced, zero pad
    }
}

// h = relu( dis[c] * ( sum_e w_e*hw'[row_e] + hw'[c] ) + b )
// One wave per node; halves process even/odd edges -> 2 distinct 64B
// segments per gather instr (fp16 rows). If pooled!=nullptr: layer-3
// mode, fuse segment_max via atomicMax (values >=0 post-relu, pooled
// zeroed) and skip the row store entirely.
__global__ __launch_bounds__(256, 4)
void k_agg(const __half* __restrict__ hw, const float* __restrict__ dis,
           const int* __restrict__ ptr, const int2* __restrict__ csr,
           const float* __restrict__ bias, const int* __restrict__ batch,
           float* __restrict__ out, float* __restrict__ pooled, int n) {
    int wid = (blockIdx.x * blockDim.x + threadIdx.x) >> 6;
    int lane = threadIdx.x & 63;
    if (wid >= n) return;
    int f = lane & 31;
    int half = lane >> 5;
    int s = ptr[wid];
    int e = ptr[wid + 1];
    float a0 = 0.0f, a1 = 0.0f, a2 = 0.0f, a3 = 0.0f;
    for (int base = s; base < e; base += 32) {
        int idxv = 0; float nrmv = 0.0f;
        int src = base + lane;
        if (lane < 32 && src < e) {
            int2 v = csr[src];
            idxv = v.x;
            nrmv = __int_as_float(v.y);
        }
        float wt[16], vt[16];
#pragma unroll
        for (int j = 0; j < 16; j++) {
            int sl = 2 * j + half;               // halves take even/odd edges
            int r = __shfl(idxv, sl, 64);
            wt[j] = __shfl(nrmv, sl, 64);
            vt[j] = __half2float(hw[(size_t)r * 32 + f]);
        }
#pragma unroll
        for (int j = 0; j < 16; j += 4) {
            a0 = fmaf(wt[j],     vt[j],     a0);
            a1 = fmaf(wt[j + 1], vt[j + 1], a1);
            a2 = fmaf(wt[j + 2], vt[j + 2], a2);
            a3 = fmaf(wt[j + 3], vt[j + 3], a3);
        }
    }
    float acc = (a0 + a1) + (a2 + a3);
    acc += __shfl_xor(acc, 32, 64);
    float dc = dis[wid];
    float r = dc * (acc + __half2float(hw[(size_t)wid * 32 + f]));
    if (half == 0 && f < 30) {
        r = fmaxf(r + bias[f], 0.0f);
        if (pooled) {
            int g = batch[wid];
            atomicMax((int*)&pooled[g * 32 + f], __float_as_int(r));
        } else {
            out[(size_t)wid * 32 + f] = r;
        }
    }
}

__global__ void k_mlp(const float* __restrict__ pooled,
                      const float* __restrict__ LW1, const float* __restrict__ Lb1,
                      const float* __restrict__ LW2, const float* __restrict__ Lb2,
                      float* __restrict__ out, int G) {
    int g = blockIdx.x * blockDim.x + threadIdx.x;
    if (g >= G) return;
    float p[30];
#pragma unroll
    for (int k = 0; k < 30; k++) p[k] = pooled[g * 32 + k];
    float o0 = Lb2[0], o1 = Lb2[1];
#pragma unroll
    for (int j = 0; j < 10; j++) {
        float hj = Lb1[j];
#pragma unroll
        for (int k = 0; k < 30; k++) hj += p[k] * LW1[k * 10 + j];
        hj = fmaxf(hj, 0.0f);
        o0 += hj * LW2[j * 2 + 0];
        o1 += hj * LW2[j * 2 + 1];
    }
    out[g * 2 + 0] = o0;
    out[g * 2 + 1] = o1;
}

extern "C" void kernel_launch(void* const* d_in, const int* in_sizes, int n_in,
                              void* d_out, int out_size, void* d_ws, size_t ws_size,
                              hipStream_t stream) {
    const float* x     = (const float*)d_in[0];
    const int*   ei    = (const int*)d_in[1];
    const int*   batch = (const int*)d_in[2];
    const float* ew    = (const float*)d_in[3];
    const float* W1 = (const float*)d_in[4];  const float* b1  = (const float*)d_in[5];
    const float* W2 = (const float*)d_in[6];  const float* b2  = (const float*)d_in[7];
    const float* W3 = (const float*)d_in[8];  const float* b3  = (const float*)d_in[9];
    const float* LW1 = (const float*)d_in[10]; const float* Lb1 = (const float*)d_in[11];
    const float* LW2 = (const float*)d_in[12]; const float* Lb2 = (const float*)d_in[13];
    float* out = (float*)d_out;

    const int N = in_sizes[2];       // batch has N entries
    const int E = in_sizes[3];       // edge_weights has E entries
    const int G = out_size / 2;
    const int* row = ei;
    const int* col = ei + E;

    const int NB = (N + 255) >> 8;   // 391 buckets (must be <= 512)

    char* p = (char*)d_ws;
    auto carve = [&](size_t bytes) -> void* {
        void* r = (void*)p;
        p += (bytes + 255) & ~(size_t)255;
        return r;
    };
    int*   ptr       = (int*)carve((size_t)(N + 1) * 4);
    float* dis       = (float*)carve((size_t)N * 4);
    int*   bcur      = (int*)carve((size_t)NB * 16 * 4);
    int2*  csr       = (int2*)carve((size_t)E * 8);
    // regionA: bucket storage (build) aliased with feature buffers (layers).
    // Layer layout: [bufA fp32: N*32*4][bufB fp16: N*32*2]. xp (fp16,
    // N*16*2) at offset 0 and y16 (fp32, N*16*4) at offset N*16*2 both
    // alias bufA; both are dead before layer-2 k_agg writes bufA.
    size_t buckBytes = (size_t)NB * CAP * 8;
    size_t featBytes = (size_t)N * 32 * 4 * 2;
    char*  regionA   = (char*)carve(buckBytes > featBytes ? buckBytes : featBytes);
    int2*  buck      = (int2*)regionA;
    float* bufA      = (float*)regionA;
    __half* xp       = (__half*)regionA;                            // N*16 fp16
    float* y16       = (float*)(regionA + (size_t)N * 16 * 2);      // N*16 fp32
    __half* bufB     = (__half*)(regionA + (size_t)N * 32 * 4);     // N*32 fp16
    float* pooled    = (float*)carve((size_t)G * 32 * 4);

    int initN = (NB * 16 > G * 32) ? NB * 16 : G * 32;

    // --- build CSR ---
    k_init<<<(initN + WG - 1) / WG, WG, 0, stream>>>(bcur, pooled, NB * 16, G * 32);
    k_bucket<<<(E + T_EDGES - 1) / T_EDGES, 1024, 0, stream>>>(row, col, ew, bcur, buck, E, NB);
    k_fuse<<<NB, 1024, 0, stream>>>(bcur, buck, dis, ptr, csr, N, NB);

    int agg_grid   = (int)(((size_t)N * 64 + WG - 1) / WG);              // 1 node/wave
    int agg16_grid = (int)(((size_t)((N + 3) / 4) * 64 + WG - 1) / WG);  // 4 nodes/wave
    int mm_grid    = (int)(((size_t)N * 32 + WG - 1) / WG);

    // layer 1 in 10-dim space: y = dc*(sum w*x'_r + x'_c), then lin1
    k_stage<<<(int)(((size_t)N * 16 + WG - 1) / WG), WG, 0, stream>>>(x, dis, xp, N);
    k_agg16<<<agg16_grid, WG, 0, stream>>>(xp, dis, ptr, csr, y16, N);
    k_lin1<<<(N + 7) / 8, 256, 0, stream>>>(y16, W1, b1, W2, dis, bufB, N);   // bufB = hw2 (fp16)
    // layer 2
    k_agg<<<agg_grid, WG, 0, stream>>>(bufB, dis, ptr, csr, b2, batch, bufA, nullptr, N); // bufA = h2
    k_matmul30<<<mm_grid, WG, 0, stream>>>(bufA, W3, dis, bufB, N);           // bufB = hw3 (fp16)
    // layer 3 + fused segment-max pool
    k_agg<<<agg_grid, WG, 0, stream>>>(bufB, dis, ptr, csr, b3, batch, nullptr, pooled, N);

    // head
    k_mlp<<<(G + WG - 1) / WG, WG, 0, stream>>>(pooled, LW1, Lb1, LW2, Lb2, out, G);
}

// Round 8
// 388.291 us; speedup vs baseline: 1.1166x; 1.0220x over previous
//
#include <hip/hip_runtime.h>
#include <hip/hip_bf16.h>
#include <hip/hip_fp16.h>

// GCN: 3x (h@W -> symmetric-norm edge aggregation -> +b -> relu),
// segment_max pool over sorted batch, 2-layer MLP head.
// R21: split k_agg into two SEPARATE kernels. R20's runtime `if(pooled)`
// branch merged store-mode and pool-mode into one binary and degraded
// the hot-loop schedule (73us vs R17's 61us at identical FETCH/VGPR).
// k_agg_store = byte-identical R17 body (store epilogue);
// k_agg_pool  = same loop, atomicMax segment-max epilogue (keeps the
// R19 pool fusion: no h3 store, no k_pool kernel). fp16 gather tables.

#define WG 256
#define CAP 9216      // bucket capacity: mean 8192, sigma ~90 -> +11 sigma
#define T_EDGES 16384 // edges per bucketing block

__global__ void k_init(int* bcur, float* pooled, int nb16, int pooledN) {
    int i = blockIdx.x * blockDim.x + threadIdx.x;
    if (i < nb16) bcur[i] = 0;
    if (i < pooledN) pooled[i] = 0.0f;
}

// Phase 1: tile-local counting scatter into 256-node buckets.
// Record packs low: (col&255) | (row<<8)   high: w bits.
__global__ __launch_bounds__(1024)
void k_bucket(const int* __restrict__ row, const int* __restrict__ col,
              const float* __restrict__ w,
              int* bcur, int2* __restrict__ buck, int E, int NB) {
    __shared__ int hist[512];
    __shared__ int base[512];
    int tid = threadIdx.x;
    for (int i = tid; i < NB; i += 1024) hist[i] = 0;
    __syncthreads();
    int start = blockIdx.x * T_EDGES;
    int end = min(start + T_EDGES, E);
    for (int i = start + tid; i < end; i += 1024)
        atomicAdd(&hist[col[i] >> 8], 1);
    __syncthreads();
    for (int i = tid; i < NB; i += 1024) {
        int h = hist[i];
        base[i] = (h > 0) ? atomicAdd(&bcur[i * 16], h) : 0;  // reserve run
        hist[i] = 0;
    }
    __syncthreads();
    for (int i = start + tid; i < end; i += 1024) {
        int c = col[i];
        int b = c >> 8;
        int off = atomicAdd(&hist[b], 1);
        int pos = base[b] + off;
        if (pos < CAP) {
            int2 pk;
            pk.x = (c & 255) | (row[i] << 8);
            pk.y = __float_as_int(w[i]);
            buck[(size_t)b * CAP + pos] = pk;
        }
    }
}

// Fused phase 2 (incl. bucket-level scan): per bucket --
// scan bcur in LDS -> bbase; pass 1: LDS count+wsum over records; write
// dis; in-bucket prefix -> ptr + cursors; pass 2 (L2-hot re-read):
// scatter records to final CSR as (row, raw w).
__global__ __launch_bounds__(1024)
void k_fuse(const int* __restrict__ bcur, const int2* __restrict__ buck,
            float* __restrict__ dis, int* __restrict__ ptr,
            int2* __restrict__ csr, int N, int NB) {
    __shared__ int lc[256];
    __shared__ float lw[256];
    __shared__ int sh[256];
    __shared__ int cur[256];
    __shared__ int sb[512];
    int b = blockIdx.x;
    int tid = threadIdx.x;
    if (tid < 512) sb[tid] = (tid < NB) ? min(bcur[tid * 16], CAP) : 0;
    if (tid < 256) { lc[tid] = 0; lw[tid] = 0.0f; }
    __syncthreads();
    for (int off = 1; off < 512; off <<= 1) {
        int v = (tid < 512 && tid >= off) ? sb[tid - off] : 0;
        __syncthreads();
        if (tid < 512) sb[tid] += v;
        __syncthreads();
    }
    int m = min(bcur[b * 16], CAP);
    int bbase = sb[b] - m;               // exclusive prefix for this bucket
    if (b == 0 && tid == 0) ptr[N] = sb[511];  // grand total
    const int2* bp = buck + (size_t)b * CAP;
    for (int i = tid; i < m; i += 1024) {
        int2 pk = bp[i];
        int lcol = pk.x & 255;
        atomicAdd(&lc[lcol], 1);
        atomicAdd(&lw[lcol], __int_as_float(pk.y));
    }
    __syncthreads();
    int lcnt = 0;
    if (tid < 256) { lcnt = lc[tid]; sh[tid] = lcnt; }
    __syncthreads();
    for (int off = 1; off < 256; off <<= 1) {
        int t = (tid >= off && tid < 256) ? sh[tid - off] : 0;
        __syncthreads();
        if (tid < 256) sh[tid] += t;
        __syncthreads();
    }
    int node = (b << 8) + tid;
    if (tid < 256) {
        int base = bbase + sh[tid] - lcnt;  // exclusive node prefix
        cur[tid] = base;
        if (node < N) {
            ptr[node] = base;
            float d = 1.0f + lw[tid];   // self-loop weight 1
            dis[node] = (d > 0.0f) ? (1.0f / sqrtf(d)) : 0.0f;
        }
    }
    __syncthreads();
    for (int i = tid; i < m; i += 1024) {
        int2 pk = bp[i];
        int lcol = pk.x & 255;
        int pos = atomicAdd(&cur[lcol], 1);
        int2 rec;
        rec.x = (int)(((unsigned)pk.x) >> 8);
        rec.y = pk.y;                    // raw w (dis folded into features)
        csr[pos] = rec;
    }
}

// x' = dis[node] * x[node]  into N x 16 fp16 rows (cols 10-15 zero)
__global__ void k_stage(const float* __restrict__ x, const float* __restrict__ dis,
                        __half* __restrict__ xp, int n) {
    int gid = blockIdx.x * blockDim.x + threadIdx.x;
    int node = gid >> 4, f = gid & 15;
    if (node < n)
        xp[(size_t)node * 16 + f] = __float2half((f < 10) ? dis[node] * x[(size_t)node * 10 + f] : 0.0f);
}

// y[c] = dis[c] * ( sum_e w_e * x'[row_e] + x'[c] )   (fp16 32B rows)
// 4 nodes per wave: quarter q owns node 4*wid+q, f = lane&15. Each
// quarter loads its own 16-record CSR chunk; shfl src (lane&48)|j.
// One gather instr = 4 distinct 32B segments. Output y fp32.
__global__ __launch_bounds__(256, 4)
void k_agg16(const __half* __restrict__ xp, const float* __restrict__ dis,
             const int* __restrict__ ptr, const int2* __restrict__ csr,
             float* __restrict__ y, int n) {
    int wid = (blockIdx.x * blockDim.x + threadIdx.x) >> 6;
    int lane = threadIdx.x & 63;
    int f = lane & 15;
    int laneq = lane & 48;
    int node = 4 * wid + (lane >> 4);
    bool valid = node < n;
    int s = 0, e = 0;
    if (valid) { s = ptr[node]; e = ptr[node + 1]; }
    int len = e - s;
    int m01 = max(__shfl(len, 0, 64), __shfl(len, 16, 64));
    int m23 = max(__shfl(len, 32, 64), __shfl(len, 48, 64));
    int maxlen = max(m01, m23);
    float a0 = 0.0f, a1 = 0.0f, a2 = 0.0f, a3 = 0.0f;
    for (int off = 0; off < maxlen; off += 16) {
        int idxv = 0; float nrmv = 0.0f;
        if (off + f < len) {
            int2 v = csr[s + off + f];
            idxv = v.x;
            nrmv = __int_as_float(v.y);
        }
        float wt[16], vt[16];
#pragma unroll
        for (int j = 0; j < 16; j++) {
            int r = __shfl(idxv, laneq | j, 64);
            wt[j] = __shfl(nrmv, laneq | j, 64);
            vt[j] = __half2float(xp[(size_t)r * 16 + f]);
        }
#pragma unroll
        for (int j = 0; j < 16; j += 4) {
            a0 = fmaf(wt[j],     vt[j],     a0);
            a1 = fmaf(wt[j + 1], vt[j + 1], a1);
            a2 = fmaf(wt[j + 2], vt[j + 2], a2);
            a3 = fmaf(wt[j + 3], vt[j + 3], a3);
        }
    }
    if (valid) {
        float acc = (a0 + a1) + (a2 + a3);
        float r = dis[node] * (acc + __half2float(xp[(size_t)node * 16 + f]));
        y[(size_t)node * 16 + f] = r;   // cols 10-15 compute to 0
    }
}

// hw2 = dis * ( relu(y @ W1 + b1) @ W2 )  -- 8 nodes/block, LDS staged.
// Output fp16 rows (stride 32 halves = 64B).
__global__ __launch_bounds__(256)
void k_lin1(const float* __restrict__ y, const float* __restrict__ W1,
            const float* __restrict__ b1, const float* __restrict__ W2,
            const float* __restrict__ dis, __half* __restrict__ out, int n) {
    __shared__ float W1s[10 * 32];
    __shared__ float W2s[30 * 32];
    __shared__ float b1s[32];
    __shared__ float ys[8][16];
    __shared__ float hs[8][32];
    int tid = threadIdx.x;
    for (int i = tid; i < 10 * 32; i += 256) { int k = i >> 5, f = i & 31; W1s[i] = (f < 30) ? W1[k * 30 + f] : 0.0f; }
    for (int i = tid; i < 30 * 32; i += 256) { int k = i >> 5, f = i & 31; W2s[i] = (f < 30) ? W2[k * 30 + f] : 0.0f; }
    if (tid < 32) b1s[tid] = (tid < 30) ? b1[tid] : 0.0f;
    int n8 = tid >> 5, f = tid & 31;
    int node = blockIdx.x * 8 + n8;
    __syncthreads();
    if (node < n && f < 16) ys[n8][f] = y[(size_t)node * 16 + f];
    __syncthreads();
    if (node < n) {
        float h = b1s[f];
#pragma unroll
        for (int k = 0; k < 10; k++) h += ys[n8][k] * W1s[k * 32 + f];
        h = fmaxf(h, 0.0f);
        if (f >= 30) h = 0.0f;
        hs[n8][f] = h;
    }
    __syncthreads();
    if (node < n) {
        float o = 0.0f;
#pragma unroll
        for (int k = 0; k < 30; k++) o += hs[n8][k] * W2s[k * 32 + f];
        out[(size_t)node * 32 + f] = __float2half(o * dis[node]);  // cols>=30 are 0
    }
}

// hw' = dis[node] * (in @ W)   (W is 30 x 30 row-major), in fp32,
// out fp16 rows stride 32 (cols 30,31 zeroed).
__global__ void k_matmul30(const float* __restrict__ in,
                           const float* __restrict__ W, const float* __restrict__ dis,
                           __half* __restrict__ out, int n) {
    __shared__ float Ws[30 * 30];
    for (int idx = threadIdx.x; idx < 30 * 30; idx += blockDim.x) Ws[idx] = W[idx];
    __syncthreads();
    int gid = blockIdx.x * blockDim.x + threadIdx.x;
    int node = gid >> 5;
    int f = gid & 31;
    if (node < n) {
        float acc = 0.0f;
        if (f < 30) {
            const float* ip = in + (size_t)node * 32;
#pragma unroll
            for (int k = 0; k < 30; k++) acc += ip[k] * Ws[k * 30 + f];
            acc *= dis[node];
        }
        out[(size_t)node * 32 + f] = __float2half(acc);   // coalesced, zero pad
    }
}

// h = relu( dis[c] * ( sum_e w_e*hw'[row_e] + hw'[c] ) + b )  -> store
// One wave per node; halves process even/odd edges -> 2 distinct 64B
// segments per gather instr (fp16 rows). R17 body, store epilogue.
__global__ __launch_bounds__(256, 4)
void k_agg_store(const __half* __restrict__ hw, const float* __restrict__ dis,
                 const int* __restrict__ ptr, const int2* __restrict__ csr,
                 const float* __restrict__ bias,
                 float* __restrict__ out, int n) {
    int wid = (blockIdx.x * blockDim.x + threadIdx.x) >> 6;
    int lane = threadIdx.x & 63;
    if (wid >= n) return;
    int f = lane & 31;
    int half = lane >> 5;
    int s = ptr[wid];
    int e = ptr[wid + 1];
    float a0 = 0.0f, a1 = 0.0f, a2 = 0.0f, a3 = 0.0f;
    for (int base = s; base < e; base += 32) {
        int idxv = 0; float nrmv = 0.0f;
        int src = base + lane;
        if (lane < 32 && src < e) {
            int2 v = csr[src];
            idxv = v.x;
            nrmv = __int_as_float(v.y);
        }
        float wt[16], vt[16];
#pragma unroll
        for (int j = 0; j < 16; j++) {
            int sl = 2 * j + half;               // halves take even/odd edges
            int r = __shfl(idxv, sl, 64);
            wt[j] = __shfl(nrmv, sl, 64);
            vt[j] = __half2float(hw[(size_t)r * 32 + f]);
        }
#pragma unroll
        for (int j = 0; j < 16; j += 4) {
            a0 = fmaf(wt[j],     vt[j],     a0);
            a1 = fmaf(wt[j + 1], vt[j + 1], a1);
            a2 = fmaf(wt[j + 2], vt[j + 2], a2);
            a3 = fmaf(wt[j + 3], vt[j + 3], a3);
        }
    }
    float acc = (a0 + a1) + (a2 + a3);
    acc += __shfl_xor(acc, 32, 64);
    float dc = dis[wid];
    float r = dc * (acc + __half2float(hw[(size_t)wid * 32 + f]));
    if (half == 0 && f < 30) {
        r += bias[f];
        out[(size_t)wid * 32 + f] = fmaxf(r, 0.0f);
    }
}

// Same loop, pool epilogue: h only feeds segment_max, so skip the row
// store and atomicMax straight into pooled (values >=0 post-relu,
// pooled zero-initialized; int-max == float-max for non-negative).
__global__ __launch_bounds__(256, 4)
void k_agg_pool(const __half* __restrict__ hw, const float* __restrict__ dis,
                const int* __restrict__ ptr, const int2* __restrict__ csr,
                const float* __restrict__ bias, const int* __restrict__ batch,
                float* __restrict__ pooled, int n) {
    int wid = (blockIdx.x * blockDim.x + threadIdx.x) >> 6;
    int lane = threadIdx.x & 63;
    if (wid >= n) return;
    int f = lane & 31;
    int half = lane >> 5;
    int s = ptr[wid];
    int e = ptr[wid + 1];
    float a0 = 0.0f, a1 = 0.0f, a2 = 0.0f, a3 = 0.0f;
    for (int base = s; base < e; base += 32) {
        int idxv = 0; float nrmv = 0.0f;
        int src = base + lane;
        if (lane < 32 && src < e) {
            int2 v = csr[src];
            idxv = v.x;
            nrmv = __int_as_float(v.y);
        }
        float wt[16], vt[16];
#pragma unroll
        for (int j = 0; j < 16; j++) {
            int sl = 2 * j + half;
            int r = __shfl(idxv, sl, 64);
            wt[j] = __shfl(nrmv, sl, 64);
            vt[j] = __half2float(hw[(size_t)r * 32 + f]);
        }
#pragma unroll
        for (int j = 0; j < 16; j += 4) {
            a0 = fmaf(wt[j],     vt[j],     a0);
            a1 = fmaf(wt[j + 1], vt[j + 1], a1);
            a2 = fmaf(wt[j + 2], vt[j + 2], a2);
            a3 = fmaf(wt[j + 3], vt[j + 3], a3);
        }
    }
    float acc = (a0 + a1) + (a2 + a3);
    acc += __shfl_xor(acc, 32, 64);
    float dc = dis[wid];
    float r = dc * (acc + __half2float(hw[(size_t)wid * 32 + f]));
    if (half == 0 && f < 30) {
        r = fmaxf(r + bias[f], 0.0f);
        int g = batch[wid];
        atomicMax((int*)&pooled[g * 32 + f], __float_as_int(r));
    }
}

__global__ void k_mlp(const float* __restrict__ pooled,
                      const float* __restrict__ LW1, const float* __restrict__ Lb1,
                      const float* __restrict__ LW2, const float* __restrict__ Lb2,
                      float* __restrict__ out, int G) {
    int g = blockIdx.x * blockDim.x + threadIdx.x;
    if (g >= G) return;
    float p[30];
#pragma unroll
    for (int k = 0; k < 30; k++) p[k] = pooled[g * 32 + k];
    float o0 = Lb2[0], o1 = Lb2[1];
#pragma unroll
    for (int j = 0; j < 10; j++) {
        float hj = Lb1[j];
#pragma unroll
        for (int k = 0; k < 30; k++) hj += p[k] * LW1[k * 10 + j];
        hj = fmaxf(hj, 0.0f);
        o0 += hj * LW2[j * 2 + 0];
        o1 += hj * LW2[j * 2 + 1];
    }
    out[g * 2 + 0] = o0;
    out[g * 2 + 1] = o1;
}

extern "C" void kernel_launch(void* const* d_in, const int* in_sizes, int n_in,
                              void* d_out, int out_size, void* d_ws, size_t ws_size,
                              hipStream_t stream) {
    const float* x     = (const float*)d_in[0];
    const int*   ei    = (const int*)d_in[1];
    const int*   batch = (const int*)d_in[2];
    const float* ew    = (const float*)d_in[3];
    const float* W1 = (const float*)d_in[4];  const float* b1  = (const float*)d_in[5];
    const float* W2 = (const float*)d_in[6];  const float* b2  = (const float*)d_in[7];
    const float* W3 = (const float*)d_in[8];  const float* b3  = (const float*)d_in[9];
    const float* LW1 = (const float*)d_in[10]; const float* Lb1 = (const float*)d_in[11];
    const float* LW2 = (const float*)d_in[12]; const float* Lb2 = (const float*)d_in[13];
    float* out = (float*)d_out;

    const int N = in_sizes[2];       // batch has N entries
    const int E = in_sizes[3];       // edge_weights has E entries
    const int G = out_size / 2;
    const int* row = ei;
    const int* col = ei + E;

    const int NB = (N + 255) >> 8;   // 391 buckets (must be <= 512)

    char* p = (char*)d_ws;
    auto carve = [&](size_t bytes) -> void* {
        void* r = (void*)p;
        p += (bytes + 255) & ~(size_t)255;
        return r;
    };
    int*   ptr       = (int*)carve((size_t)(N + 1) * 4);
    float* dis       = (float*)carve((size_t)N * 4);
    int*   bcur      = (int*)carve((size_t)NB * 16 * 4);
    int2*  csr       = (int2*)carve((size_t)E * 8);
    // regionA: bucket storage (build) aliased with feature buffers (layers).
    // Layer layout: [bufA fp32: N*32*4][bufB fp16: N*32*2]. xp (fp16,
    // N*16*2) at offset 0 and y16 (fp32, N*16*4) at offset N*16*2 both
    // alias bufA; both are dead before layer-2 k_agg writes bufA.
    size_t buckBytes = (size_t)NB * CAP * 8;
    size_t featBytes = (size_t)N * 32 * 4 * 2;
    char*  regionA   = (char*)carve(buckBytes > featBytes ? buckBytes : featBytes);
    int2*  buck      = (int2*)regionA;
    float* bufA      = (float*)regionA;
    __half* xp       = (__half*)regionA;                            // N*16 fp16
    float* y16       = (float*)(regionA + (size_t)N * 16 * 2);      // N*16 fp32
    __half* bufB     = (__half*)(regionA + (size_t)N * 32 * 4);     // N*32 fp16
    float* pooled    = (float*)carve((size_t)G * 32 * 4);

    int initN = (NB * 16 > G * 32) ? NB * 16 : G * 32;

    // --- build CSR ---
    k_init<<<(initN + WG - 1) / WG, WG, 0, stream>>>(bcur, pooled, NB * 16, G * 32);
    k_bucket<<<(E + T_EDGES - 1) / T_EDGES, 1024, 0, stream>>>(row, col, ew, bcur, buck, E, NB);
    k_fuse<<<NB, 1024, 0, stream>>>(bcur, buck, dis, ptr, csr, N, NB);

    int agg_grid   = (int)(((size_t)N * 64 + WG - 1) / WG);              // 1 node/wave
    int agg16_grid = (int)(((size_t)((N + 3) / 4) * 64 + WG - 1) / WG);  // 4 nodes/wave
    int mm_grid    = (int)(((size_t)N * 32 + WG - 1) / WG);

    // layer 1 in 10-dim space: y = dc*(sum w*x'_r + x'_c), then lin1
    k_stage<<<(int)(((size_t)N * 16 + WG - 1) / WG), WG, 0, stream>>>(x, dis, xp, N);
    k_agg16<<<agg16_grid, WG, 0, stream>>>(xp, dis, ptr, csr, y16, N);
    k_lin1<<<(N + 7) / 8, 256, 0, stream>>>(y16, W1, b1, W2, dis, bufB, N);   // bufB = hw2 (fp16)
    // layer 2
    k_agg_store<<<agg_grid, WG, 0, stream>>>(bufB, dis, ptr, csr, b2, bufA, N); // bufA = h2
    k_matmul30<<<mm_grid, WG, 0, stream>>>(bufA, W3, dis, bufB, N);           // bufB = hw3 (fp16)
    // layer 3 + fused segment-max pool
    k_agg_pool<<<agg_grid, WG, 0, stream>>>(bufB, dis, ptr, csr, b3, batch, pooled, N);

    // head
    k_mlp<<<(G + WG - 1) / WG, WG, 0, stream>>>(pooled, LW1, Lb1, LW2, Lb2, out, G);
}

// Round 9
// 383.401 us; speedup vs baseline: 1.1309x; 1.0128x over previous
//
#include <hip/hip_runtime.h>
#include <hip/hip_bf16.h>
#include <hip/hip_fp16.h>

// GCN: 3x (h@W -> symmetric-norm edge aggregation -> +b -> relu),
// segment_max pool over sorted batch, 2-layer MLP head.
// R22: LDS pre-reduction in k_agg_pool's epilogue. R21 counters showed
// WRITE_SIZE=12.5MB on the pool kernel = 3M atomicMax x 4B write-through
// to HBM (~200 serialized RMW per address) -> the +11us vs store mode.
// Block's 4 waves = 4 consecutive nodes; sorted batch (~195 nodes/grp)
// means ~98% of blocks are single-group: reduce the 4 rows in LDS, one
// atomic set per block (per-node fallback at boundaries). Atomics 3M ->
// 0.78M. Hot loop untouched (R21/R17 body). fp16 gather tables.

#define WG 256
#define CAP 9216      // bucket capacity: mean 8192, sigma ~90 -> +11 sigma
#define T_EDGES 16384 // edges per bucketing block

__global__ void k_init(int* bcur, float* pooled, int nb16, int pooledN) {
    int i = blockIdx.x * blockDim.x + threadIdx.x;
    if (i < nb16) bcur[i] = 0;
    if (i < pooledN) pooled[i] = 0.0f;
}

// Phase 1: tile-local counting scatter into 256-node buckets.
// Record packs low: (col&255) | (row<<8)   high: w bits.
__global__ __launch_bounds__(1024)
void k_bucket(const int* __restrict__ row, const int* __restrict__ col,
              const float* __restrict__ w,
              int* bcur, int2* __restrict__ buck, int E, int NB) {
    __shared__ int hist[512];
    __shared__ int base[512];
    int tid = threadIdx.x;
    for (int i = tid; i < NB; i += 1024) hist[i] = 0;
    __syncthreads();
    int start = blockIdx.x * T_EDGES;
    int end = min(start + T_EDGES, E);
    for (int i = start + tid; i < end; i += 1024)
        atomicAdd(&hist[col[i] >> 8], 1);
    __syncthreads();
    for (int i = tid; i < NB; i += 1024) {
        int h = hist[i];
        base[i] = (h > 0) ? atomicAdd(&bcur[i * 16], h) : 0;  // reserve run
        hist[i] = 0;
    }
    __syncthreads();
    for (int i = start + tid; i < end; i += 1024) {
        int c = col[i];
        int b = c >> 8;
        int off = atomicAdd(&hist[b], 1);
        int pos = base[b] + off;
        if (pos < CAP) {
            int2 pk;
            pk.x = (c & 255) | (row[i] << 8);
            pk.y = __float_as_int(w[i]);
            buck[(size_t)b * CAP + pos] = pk;
        }
    }
}

// Fused phase 2 (incl. bucket-level scan): per bucket --
// scan bcur in LDS -> bbase; pass 1: LDS count+wsum over records; write
// dis; in-bucket prefix -> ptr + cursors; pass 2 (L2-hot re-read):
// scatter records to final CSR as (row, raw w).
__global__ __launch_bounds__(1024)
void k_fuse(const int* __restrict__ bcur, const int2* __restrict__ buck,
            float* __restrict__ dis, int* __restrict__ ptr,
            int2* __restrict__ csr, int N, int NB) {
    __shared__ int lc[256];
    __shared__ float lw[256];
    __shared__ int sh[256];
    __shared__ int cur[256];
    __shared__ int sb[512];
    int b = blockIdx.x;
    int tid = threadIdx.x;
    if (tid < 512) sb[tid] = (tid < NB) ? min(bcur[tid * 16], CAP) : 0;
    if (tid < 256) { lc[tid] = 0; lw[tid] = 0.0f; }
    __syncthreads();
    for (int off = 1; off < 512; off <<= 1) {
        int v = (tid < 512 && tid >= off) ? sb[tid - off] : 0;
        __syncthreads();
        if (tid < 512) sb[tid] += v;
        __syncthreads();
    }
    int m = min(bcur[b * 16], CAP);
    int bbase = sb[b] - m;               // exclusive prefix for this bucket
    if (b == 0 && tid == 0) ptr[N] = sb[511];  // grand total
    const int2* bp = buck + (size_t)b * CAP;
    for (int i = tid; i < m; i += 1024) {
        int2 pk = bp[i];
        int lcol = pk.x & 255;
        atomicAdd(&lc[lcol], 1);
        atomicAdd(&lw[lcol], __int_as_float(pk.y));
    }
    __syncthreads();
    int lcnt = 0;
    if (tid < 256) { lcnt = lc[tid]; sh[tid] = lcnt; }
    __syncthreads();
    for (int off = 1; off < 256; off <<= 1) {
        int t = (tid >= off && tid < 256) ? sh[tid - off] : 0;
        __syncthreads();
        if (tid < 256) sh[tid] += t;
        __syncthreads();
    }
    int node = (b << 8) + tid;
    if (tid < 256) {
        int base = bbase + sh[tid] - lcnt;  // exclusive node prefix
        cur[tid] = base;
        if (node < N) {
            ptr[node] = base;
            float d = 1.0f + lw[tid];   // self-loop weight 1
            dis[node] = (d > 0.0f) ? (1.0f / sqrtf(d)) : 0.0f;
        }
    }
    __syncthreads();
    for (int i = tid; i < m; i += 1024) {
        int2 pk = bp[i];
        int lcol = pk.x & 255;
        int pos = atomicAdd(&cur[lcol], 1);
        int2 rec;
        rec.x = (int)(((unsigned)pk.x) >> 8);
        rec.y = pk.y;                    // raw w (dis folded into features)
        csr[pos] = rec;
    }
}

// x' = dis[node] * x[node]  into N x 16 fp16 rows (cols 10-15 zero)
__global__ void k_stage(const float* __restrict__ x, const float* __restrict__ dis,
                        __half* __restrict__ xp, int n) {
    int gid = blockIdx.x * blockDim.x + threadIdx.x;
    int node = gid >> 4, f = gid & 15;
    if (node < n)
        xp[(size_t)node * 16 + f] = __float2half((f < 10) ? dis[node] * x[(size_t)node * 10 + f] : 0.0f);
}

// y[c] = dis[c] * ( sum_e w_e * x'[row_e] + x'[c] )   (fp16 32B rows)
// 4 nodes per wave: quarter q owns node 4*wid+q, f = lane&15. Each
// quarter loads its own 16-record CSR chunk; shfl src (lane&48)|j.
// One gather instr = 4 distinct 32B segments. Output y fp32.
__global__ __launch_bounds__(256, 4)
void k_agg16(const __half* __restrict__ xp, const float* __restrict__ dis,
             const int* __restrict__ ptr, const int2* __restrict__ csr,
             float* __restrict__ y, int n) {
    int wid = (blockIdx.x * blockDim.x + threadIdx.x) >> 6;
    int lane = threadIdx.x & 63;
    int f = lane & 15;
    int laneq = lane & 48;
    int node = 4 * wid + (lane >> 4);
    bool valid = node < n;
    int s = 0, e = 0;
    if (valid) { s = ptr[node]; e = ptr[node + 1]; }
    int len = e - s;
    int m01 = max(__shfl(len, 0, 64), __shfl(len, 16, 64));
    int m23 = max(__shfl(len, 32, 64), __shfl(len, 48, 64));
    int maxlen = max(m01, m23);
    float a0 = 0.0f, a1 = 0.0f, a2 = 0.0f, a3 = 0.0f;
    for (int off = 0; off < maxlen; off += 16) {
        int idxv = 0; float nrmv = 0.0f;
        if (off + f < len) {
            int2 v = csr[s + off + f];
            idxv = v.x;
            nrmv = __int_as_float(v.y);
        }
        float wt[16], vt[16];
#pragma unroll
        for (int j = 0; j < 16; j++) {
            int r = __shfl(idxv, laneq | j, 64);
            wt[j] = __shfl(nrmv, laneq | j, 64);
            vt[j] = __half2float(xp[(size_t)r * 16 + f]);
        }
#pragma unroll
        for (int j = 0; j < 16; j += 4) {
            a0 = fmaf(wt[j],     vt[j],     a0);
            a1 = fmaf(wt[j + 1], vt[j + 1], a1);
            a2 = fmaf(wt[j + 2], vt[j + 2], a2);
            a3 = fmaf(wt[j + 3], vt[j + 3], a3);
        }
    }
    if (valid) {
        float acc = (a0 + a1) + (a2 + a3);
        float r = dis[node] * (acc + __half2float(xp[(size_t)node * 16 + f]));
        y[(size_t)node * 16 + f] = r;   // cols 10-15 compute to 0
    }
}

// hw2 = dis * ( relu(y @ W1 + b1) @ W2 )  -- 8 nodes/block, LDS staged.
// Output fp16 rows (stride 32 halves = 64B).
__global__ __launch_bounds__(256)
void k_lin1(const float* __restrict__ y, const float* __restrict__ W1,
            const float* __restrict__ b1, const float* __restrict__ W2,
            const float* __restrict__ dis, __half* __restrict__ out, int n) {
    __shared__ float W1s[10 * 32];
    __shared__ float W2s[30 * 32];
    __shared__ float b1s[32];
    __shared__ float ys[8][16];
    __shared__ float hs[8][32];
    int tid = threadIdx.x;
    for (int i = tid; i < 10 * 32; i += 256) { int k = i >> 5, f = i & 31; W1s[i] = (f < 30) ? W1[k * 30 + f] : 0.0f; }
    for (int i = tid; i < 30 * 32; i += 256) { int k = i >> 5, f = i & 31; W2s[i] = (f < 30) ? W2[k * 30 + f] : 0.0f; }
    if (tid < 32) b1s[tid] = (tid < 30) ? b1[tid] : 0.0f;
    int n8 = tid >> 5, f = tid & 31;
    int node = blockIdx.x * 8 + n8;
    __syncthreads();
    if (node < n && f < 16) ys[n8][f] = y[(size_t)node * 16 + f];
    __syncthreads();
    if (node < n) {
        float h = b1s[f];
#pragma unroll
        for (int k = 0; k < 10; k++) h += ys[n8][k] * W1s[k * 32 + f];
        h = fmaxf(h, 0.0f);
        if (f >= 30) h = 0.0f;
        hs[n8][f] = h;
    }
    __syncthreads();
    if (node < n) {
        float o = 0.0f;
#pragma unroll
        for (int k = 0; k < 30; k++) o += hs[n8][k] * W2s[k * 32 + f];
        out[(size_t)node * 32 + f] = __float2half(o * dis[node]);  // cols>=30 are 0
    }
}

// hw' = dis[node] * (in @ W)   (W is 30 x 30 row-major), in fp32,
// out fp16 rows stride 32 (cols 30,31 zeroed).
__global__ void k_matmul30(const float* __restrict__ in,
                           const float* __restrict__ W, const float* __restrict__ dis,
                           __half* __restrict__ out, int n) {
    __shared__ float Ws[30 * 30];
    for (int idx = threadIdx.x; idx < 30 * 30; idx += blockDim.x) Ws[idx] = W[idx];
    __syncthreads();
    int gid = blockIdx.x * blockDim.x + threadIdx.x;
    int node = gid >> 5;
    int f = gid & 31;
    if (node < n) {
        float acc = 0.0f;
        if (f < 30) {
            const float* ip = in + (size_t)node * 32;
#pragma unroll
            for (int k = 0; k < 30; k++) acc += ip[k] * Ws[k * 30 + f];
            acc *= dis[node];
        }
        out[(size_t)node * 32 + f] = __float2half(acc);   // coalesced, zero pad
    }
}

// h = relu( dis[c] * ( sum_e w_e*hw'[row_e] + hw'[c] ) + b )  -> store
// One wave per node; halves process even/odd edges -> 2 distinct 64B
// segments per gather instr (fp16 rows). R17 body, store epilogue.
__global__ __launch_bounds__(256, 4)
void k_agg_store(const __half* __restrict__ hw, const float* __restrict__ dis,
                 const int* __restrict__ ptr, const int2* __restrict__ csr,
                 const float* __restrict__ bias,
                 float* __restrict__ out, int n) {
    int wid = (blockIdx.x * blockDim.x + threadIdx.x) >> 6;
    int lane = threadIdx.x & 63;
    if (wid >= n) return;
    int f = lane & 31;
    int half = lane >> 5;
    int s = ptr[wid];
    int e = ptr[wid + 1];
    float a0 = 0.0f, a1 = 0.0f, a2 = 0.0f, a3 = 0.0f;
    for (int base = s; base < e; base += 32) {
        int idxv = 0; float nrmv = 0.0f;
        int src = base + lane;
        if (lane < 32 && src < e) {
            int2 v = csr[src];
            idxv = v.x;
            nrmv = __int_as_float(v.y);
        }
        float wt[16], vt[16];
#pragma unroll
        for (int j = 0; j < 16; j++) {
            int sl = 2 * j + half;               // halves take even/odd edges
            int r = __shfl(idxv, sl, 64);
            wt[j] = __shfl(nrmv, sl, 64);
            vt[j] = __half2float(hw[(size_t)r * 32 + f]);
        }
#pragma unroll
        for (int j = 0; j < 16; j += 4) {
            a0 = fmaf(wt[j],     vt[j],     a0);
            a1 = fmaf(wt[j + 1], vt[j + 1], a1);
            a2 = fmaf(wt[j + 2], vt[j + 2], a2);
            a3 = fmaf(wt[j + 3], vt[j + 3], a3);
        }
    }
    float acc = (a0 + a1) + (a2 + a3);
    acc += __shfl_xor(acc, 32, 64);
    float dc = dis[wid];
    float r = dc * (acc + __half2float(hw[(size_t)wid * 32 + f]));
    if (half == 0 && f < 30) {
        r += bias[f];
        out[(size_t)wid * 32 + f] = fmaxf(r, 0.0f);
    }
}

// Same loop, pool epilogue with LDS block pre-reduction: the block's 4
// waves (4 consecutive nodes, sorted batch) drop their 30-value rows in
// LDS; wave 0 maxes across nodes and issues ONE atomic set when all 4
// nodes share a group (~98% of blocks), per-node atomics otherwise.
// Cuts write-through atomic traffic 4x (3M -> 0.78M RMW).
__global__ __launch_bounds__(256, 4)
void k_agg_pool(const __half* __restrict__ hw, const float* __restrict__ dis,
                const int* __restrict__ ptr, const int2* __restrict__ csr,
                const float* __restrict__ bias, const int* __restrict__ batch,
                float* __restrict__ pooled, int n) {
    __shared__ float red[4][32];
    __shared__ int grp[4];
    int wid = (blockIdx.x * blockDim.x + threadIdx.x) >> 6;
    int lane = threadIdx.x & 63;
    int f = lane & 31;
    int half = lane >> 5;
    bool valid = wid < n;
    int s = 0, e = 0;
    if (valid) { s = ptr[wid]; e = ptr[wid + 1]; }
    float a0 = 0.0f, a1 = 0.0f, a2 = 0.0f, a3 = 0.0f;
    for (int base = s; base < e; base += 32) {
        int idxv = 0; float nrmv = 0.0f;
        int src = base + lane;
        if (lane < 32 && src < e) {
            int2 v = csr[src];
            idxv = v.x;
            nrmv = __int_as_float(v.y);
        }
        float wt[16], vt[16];
#pragma unroll
        for (int j = 0; j < 16; j++) {
            int sl = 2 * j + half;
            int r = __shfl(idxv, sl, 64);
            wt[j] = __shfl(nrmv, sl, 64);
            vt[j] = __half2float(hw[(size_t)r * 32 + f]);
        }
#pragma unroll
        for (int j = 0; j < 16; j += 4) {
            a0 = fmaf(wt[j],     vt[j],     a0);
            a1 = fmaf(wt[j + 1], vt[j + 1], a1);
            a2 = fmaf(wt[j + 2], vt[j + 2], a2);
            a3 = fmaf(wt[j + 3], vt[j + 3], a3);
        }
    }
    float acc = (a0 + a1) + (a2 + a3);
    acc += __shfl_xor(acc, 32, 64);
    float rv = 0.0f;
    if (valid && half == 0 && f < 30) {
        float dc = dis[wid];
        float r = dc * (acc + __half2float(hw[(size_t)wid * 32 + f]));
        rv = fmaxf(r + bias[f], 0.0f);
    }
    int w = threadIdx.x >> 6;                 // wave index in block (0..3)
    if (half == 0) red[w][f] = rv;            // f>=30 lanes write 0
    if (lane == 0) grp[w] = valid ? batch[wid] : -1;
    __syncthreads();
    if (w == 0 && half == 0 && f < 30) {
        int g0 = grp[0], g1 = grp[1], g2 = grp[2], g3 = grp[3];
        if (g0 >= 0 && g0 == g1 && g0 == g2 && g0 == g3) {
            float m = fmaxf(fmaxf(red[0][f], red[1][f]), fmaxf(red[2][f], red[3][f]));
            atomicMax((int*)&pooled[g0 * 32 + f], __float_as_int(m));
        } else {
            if (g0 >= 0) atomicMax((int*)&pooled[g0 * 32 + f], __float_as_int(red[0][f]));
            if (g1 >= 0) atomicMax((int*)&pooled[g1 * 32 + f], __float_as_int(red[1][f]));
            if (g2 >= 0) atomicMax((int*)&pooled[g2 * 32 + f], __float_as_int(red[2][f]));
            if (g3 >= 0) atomicMax((int*)&pooled[g3 * 32 + f], __float_as_int(red[3][f]));
        }
    }
}

__global__ void k_mlp(const float* __restrict__ pooled,
                      const float* __restrict__ LW1, const float* __restrict__ Lb1,
                      const float* __restrict__ LW2, const float* __restrict__ Lb2,
                      float* __restrict__ out, int G) {
    int g = blockIdx.x * blockDim.x + threadIdx.x;
    if (g >= G) return;
    float p[30];
#pragma unroll
    for (int k = 0; k < 30; k++) p[k] = pooled[g * 32 + k];
    float o0 = Lb2[0], o1 = Lb2[1];
#pragma unroll
    for (int j = 0; j < 10; j++) {
        float hj = Lb1[j];
#pragma unroll
        for (int k = 0; k < 30; k++) hj += p[k] * LW1[k * 10 + j];
        hj = fmaxf(hj, 0.0f);
        o0 += hj * LW2[j * 2 + 0];
        o1 += hj * LW2[j * 2 + 1];
    }
    out[g * 2 + 0] = o0;
    out[g * 2 + 1] = o1;
}

extern "C" void kernel_launch(void* const* d_in, const int* in_sizes, int n_in,
                              void* d_out, int out_size, void* d_ws, size_t ws_size,
                              hipStream_t stream) {
    const float* x     = (const float*)d_in[0];
    const int*   ei    = (const int*)d_in[1];
    const int*   batch = (const int*)d_in[2];
    const float* ew    = (const float*)d_in[3];
    const float* W1 = (const float*)d_in[4];  const float* b1  = (const float*)d_in[5];
    const float* W2 = (const float*)d_in[6];  const float* b2  = (const float*)d_in[7];
    const float* W3 = (const float*)d_in[8];  const float* b3  = (const float*)d_in[9];
    const float* LW1 = (const float*)d_in[10]; const float* Lb1 = (const float*)d_in[11];
    const float* LW2 = (const float*)d_in[12]; const float* Lb2 = (const float*)d_in[13];
    float* out = (float*)d_out;

    const int N = in_sizes[2];       // batch has N entries
    const int E = in_sizes[3];       // edge_weights has E entries
    const int G = out_size / 2;
    const int* row = ei;
    const int* col = ei + E;

    const int NB = (N + 255) >> 8;   // 391 buckets (must be <= 512)

    char* p = (char*)d_ws;
    auto carve = [&](size_t bytes) -> void* {
        void* r = (void*)p;
        p += (bytes + 255) & ~(size_t)255;
        return r;
    };
    int*   ptr       = (int*)carve((size_t)(N + 1) * 4);
    float* dis       = (float*)carve((size_t)N * 4);
    int*   bcur      = (int*)carve((size_t)NB * 16 * 4);
    int2*  csr       = (int2*)carve((size_t)E * 8);
    // regionA: bucket storage (build) aliased with feature buffers (layers).
    // Layer layout: [bufA fp32: N*32*4][bufB fp16: N*32*2]. xp (fp16,
    // N*16*2) at offset 0 and y16 (fp32, N*16*4) at offset N*16*2 both
    // alias bufA; both are dead before layer-2 k_agg writes bufA.
    size_t buckBytes = (size_t)NB * CAP * 8;
    size_t featBytes = (size_t)N * 32 * 4 * 2;
    char*  regionA   = (char*)carve(buckBytes > featBytes ? buckBytes : featBytes);
    int2*  buck      = (int2*)regionA;
    float* bufA      = (float*)regionA;
    __half* xp       = (__half*)regionA;                            // N*16 fp16
    float* y16       = (float*)(regionA + (size_t)N * 16 * 2);      // N*16 fp32
    __half* bufB     = (__half*)(regionA + (size_t)N * 32 * 4);     // N*32 fp16
    float* pooled    = (float*)carve((size_t)G * 32 * 4);

    int initN = (NB * 16 > G * 32) ? NB * 16 : G * 32;

    // --- build CSR ---
    k_init<<<(initN + WG - 1) / WG, WG, 0, stream>>>(bcur, pooled, NB * 16, G * 32);
    k_bucket<<<(E + T_EDGES - 1) / T_EDGES, 1024, 0, stream>>>(row, col, ew, bcur, buck, E, NB);
    k_fuse<<<NB, 1024, 0, stream>>>(bcur, buck, dis, ptr, csr, N, NB);

    int agg_grid   = (int)(((size_t)N * 64 + WG - 1) / WG);              // 1 node/wave
    int agg16_grid = (int)(((size_t)((N + 3) / 4) * 64 + WG - 1) / WG);  // 4 nodes/wave
    int mm_grid    = (int)(((size_t)N * 32 + WG - 1) / WG);

    // layer 1 in 10-dim space: y = dc*(sum w*x'_r + x'_c), then lin1
    k_stage<<<(int)(((size_t)N * 16 + WG - 1) / WG), WG, 0, stream>>>(x, dis, xp, N);
    k_agg16<<<agg16_grid, WG, 0, stream>>>(xp, dis, ptr, csr, y16, N);
    k_lin1<<<(N + 7) / 8, 256, 0, stream>>>(y16, W1, b1, W2, dis, bufB, N);   // bufB = hw2 (fp16)
    // layer 2
    k_agg_store<<<agg_grid, WG, 0, stream>>>(bufB, dis, ptr, csr, b2, bufA, N); // bufA = h2
    k_matmul30<<<mm_grid, WG, 0, stream>>>(bufA, W3, dis, bufB, N);           // bufB = hw3 (fp16)
    // layer 3 + fused segment-max pool (LDS pre-reduced atomics)
    k_agg_pool<<<agg_grid, WG, 0, stream>>>(bufB, dis, ptr, csr, b3, batch, pooled, N);

    // head
    k_mlp<<<(G + WG - 1) / WG, WG, 0, stream>>>(pooled, LW1, Lb1, LW2, Lb2, out, G);
}